// Round 2
// baseline (11213.409 us; speedup 1.0000x reference)
//
#include <hip/hip_runtime.h>

#define NN 100000
#define EE 300000
#define DIN 128
#define HD  256
#define HD2 512
#define NL  4
#define NG  512
#define BN_EPS 1e-5f

// ---------------------------------------------------------------------------
// Input projection GEMM: C[M,NC] = relu(A @ B + bias). BM=BN=64, BK=16,
// 256 threads, 4x4 micro-tile.
// ---------------------------------------------------------------------------
__global__ __launch_bounds__(256) void gemm_in_kernel(
    const float* __restrict__ A, const float* __restrict__ B,
    const float* __restrict__ bias, float* __restrict__ C,
    int M, int K, int NC)
{
    constexpr int BK = 16;
    __shared__ float As[BK][64 + 4];
    __shared__ float Bs[BK][64 + 4];

    const int tid  = threadIdx.x;
    const int row0 = blockIdx.y * 64;
    const int col0 = blockIdx.x * 64;
    const int tx   = tid & 15;
    const int ty   = tid >> 4;

    const int am = tid >> 2;
    const int ak = (tid & 3) << 2;
    const int bk = tid >> 4;
    const int bn = (tid & 15) << 2;

    const int  arow   = row0 + am;
    const bool avalid = arow < M;
    const float* Ap = A + (size_t)arow * K + ak;
    const float* Bp = B + (size_t)bk * NC + col0 + bn;

    float acc[4][4] = {};

    for (int k0 = 0; k0 < K; k0 += BK) {
        float4 av = make_float4(0.f, 0.f, 0.f, 0.f);
        if (avalid) av = *(const float4*)(Ap + k0);
        As[ak + 0][am] = av.x;  As[ak + 1][am] = av.y;
        As[ak + 2][am] = av.z;  As[ak + 3][am] = av.w;
        *(float4*)&Bs[bk][bn] = *(const float4*)(Bp + (size_t)k0 * NC);
        __syncthreads();
#pragma unroll
        for (int kk = 0; kk < BK; ++kk) {
            const float a0 = As[kk][ty * 4 + 0];
            const float a1 = As[kk][ty * 4 + 1];
            const float a2 = As[kk][ty * 4 + 2];
            const float a3 = As[kk][ty * 4 + 3];
            const float b0 = Bs[kk][tx * 4 + 0];
            const float b1 = Bs[kk][tx * 4 + 1];
            const float b2 = Bs[kk][tx * 4 + 2];
            const float b3 = Bs[kk][tx * 4 + 3];
            acc[0][0] += a0 * b0; acc[0][1] += a0 * b1; acc[0][2] += a0 * b2; acc[0][3] += a0 * b3;
            acc[1][0] += a1 * b0; acc[1][1] += a1 * b1; acc[1][2] += a1 * b2; acc[1][3] += a1 * b3;
            acc[2][0] += a2 * b0; acc[2][1] += a2 * b1; acc[2][2] += a2 * b2; acc[2][3] += a2 * b3;
            acc[3][0] += a3 * b0; acc[3][1] += a3 * b1; acc[3][2] += a3 * b2; acc[3][3] += a3 * b3;
        }
        __syncthreads();
    }

    const float4 bv = *(const float4*)(bias + col0 + tx * 4);
#pragma unroll
    for (int i = 0; i < 4; ++i) {
        const int r = row0 + ty * 4 + i;
        if (r < M) {
            float4 v;
            v.x = fmaxf(acc[i][0] + bv.x, 0.f);
            v.y = fmaxf(acc[i][1] + bv.y, 0.f);
            v.z = fmaxf(acc[i][2] + bv.z, 0.f);
            v.w = fmaxf(acc[i][3] + bv.w, 0.f);
            *(float4*)(C + (size_t)r * NC + col0 + tx * 4) = v;
        }
    }
}

// ---------------------------------------------------------------------------
// Fused GIN MLP: Z <- (relu(Z @ W1 + b1)) @ W2 + b2, in-place per 32-row tile.
// Hidden (32x512) lives in LDS, processed in 4 chunks of 128 cols.
// LDS: As 33.3KB + Ws 16.6KB + Hs 16.9KB = 66.8KB -> 2 blocks/CU.
// ---------------------------------------------------------------------------
__global__ __launch_bounds__(256) void fused_mlp_kernel(
    float* __restrict__ Z, const float* __restrict__ W1,
    const float* __restrict__ b1, const float* __restrict__ W2,
    const float* __restrict__ b2, int M)
{
    constexpr int RT = 32;
    __shared__ float As[RT][HD + 4];     // A tile (rows x K1)
    __shared__ float Ws[16][HD + 4];     // W1 (16x128) / W2 (16x256) K-slice
    __shared__ float Hs[RT][128 + 4];    // hidden chunk, post-relu

    const int tid  = threadIdx.x;
    const int row0 = blockIdx.x * RT;

    // stage A tile: 32x256 floats = 2048 float4, 8 per thread
#pragma unroll
    for (int i = 0; i < 8; ++i) {
        const int idx = tid + i * 256;
        const int r = idx >> 6;              // HD/4 = 64 float4 per row
        const int c = (idx & 63) << 2;
        const int gr = row0 + r;
        float4 v = make_float4(0.f, 0.f, 0.f, 0.f);
        if (gr < M) v = *(const float4*)(Z + (size_t)gr * HD + c);
        *(float4*)&As[r][c] = v;
    }

    const int ty = tid >> 5;     // 0..7  -> rows ty*4..+3
    const int tx = tid & 31;     // 0..31 -> s1 cols tx*4..+3 ; s2 cols tx*8..+7

    float acc2[4][8] = {};       // z accumulator: rows ty*4+i, cols tx*8+j

    for (int mc = 0; mc < 4; ++mc) {
        // ---- stage 1: Hs = relu(As @ W1[:, mc*128 .. +128] + b1c) ----
        float acc1[4][4] = {};
        for (int k0 = 0; k0 < HD; k0 += 16) {
            __syncthreads();      // prior Ws consumers done
#pragma unroll
            for (int j = 0; j < 2; ++j) {
                const int idx = tid + j * 256;          // 512 float4 total
                const int kk = idx >> 5;                // 32 float4 per row
                const int c  = (idx & 31) << 2;
                *(float4*)&Ws[kk][c] =
                    *(const float4*)(W1 + (size_t)(k0 + kk) * HD2 + mc * 128 + c);
            }
            __syncthreads();
#pragma unroll
            for (int kk = 0; kk < 16; ++kk) {
                const float a0 = As[ty * 4 + 0][k0 + kk];
                const float a1 = As[ty * 4 + 1][k0 + kk];
                const float a2 = As[ty * 4 + 2][k0 + kk];
                const float a3 = As[ty * 4 + 3][k0 + kk];
                const float4 bv = *(const float4*)&Ws[kk][tx * 4];
                acc1[0][0] += a0 * bv.x; acc1[0][1] += a0 * bv.y; acc1[0][2] += a0 * bv.z; acc1[0][3] += a0 * bv.w;
                acc1[1][0] += a1 * bv.x; acc1[1][1] += a1 * bv.y; acc1[1][2] += a1 * bv.z; acc1[1][3] += a1 * bv.w;
                acc1[2][0] += a2 * bv.x; acc1[2][1] += a2 * bv.y; acc1[2][2] += a2 * bv.z; acc1[2][3] += a2 * bv.w;
                acc1[3][0] += a3 * bv.x; acc1[3][1] += a3 * bv.y; acc1[3][2] += a3 * bv.z; acc1[3][3] += a3 * bv.w;
            }
        }
        const float4 b1v = *(const float4*)(b1 + mc * 128 + tx * 4);
#pragma unroll
        for (int i = 0; i < 4; ++i) {
            float4 h;
            h.x = fmaxf(acc1[i][0] + b1v.x, 0.f);
            h.y = fmaxf(acc1[i][1] + b1v.y, 0.f);
            h.z = fmaxf(acc1[i][2] + b1v.z, 0.f);
            h.w = fmaxf(acc1[i][3] + b1v.w, 0.f);
            *(float4*)&Hs[ty * 4 + i][tx * 4] = h;
        }

        // ---- stage 2: acc2 += Hs @ W2[mc*128 .. +128, :] ----
        for (int k0 = 0; k0 < 128; k0 += 16) {
            __syncthreads();      // Hs writes visible; prior Ws consumers done
#pragma unroll
            for (int j = 0; j < 4; ++j) {
                const int idx = tid + j * 256;          // 1024 float4 total
                const int kk = idx >> 6;                // 64 float4 per row
                const int c  = (idx & 63) << 2;
                *(float4*)&Ws[kk][c] =
                    *(const float4*)(W2 + (size_t)(mc * 128 + k0 + kk) * HD + c);
            }
            __syncthreads();
#pragma unroll
            for (int kk = 0; kk < 16; ++kk) {
                const float a0 = Hs[ty * 4 + 0][k0 + kk];
                const float a1 = Hs[ty * 4 + 1][k0 + kk];
                const float a2 = Hs[ty * 4 + 2][k0 + kk];
                const float a3 = Hs[ty * 4 + 3][k0 + kk];
                const float4 w0 = *(const float4*)&Ws[kk][tx * 8];
                const float4 w1 = *(const float4*)&Ws[kk][tx * 8 + 4];
#pragma unroll
                for (int i = 0; i < 4; ++i) {
                    const float a = (i == 0) ? a0 : (i == 1) ? a1 : (i == 2) ? a2 : a3;
                    acc2[i][0] += a * w0.x; acc2[i][1] += a * w0.y;
                    acc2[i][2] += a * w0.z; acc2[i][3] += a * w0.w;
                    acc2[i][4] += a * w1.x; acc2[i][5] += a * w1.y;
                    acc2[i][6] += a * w1.z; acc2[i][7] += a * w1.w;
                }
            }
        }
    }

    // epilogue: Z[r][c] = acc2 + b2 (no relu; BN follows)
    const float4 b2v0 = *(const float4*)(b2 + tx * 8);
    const float4 b2v1 = *(const float4*)(b2 + tx * 8 + 4);
#pragma unroll
    for (int i = 0; i < 4; ++i) {
        const int r = row0 + ty * 4 + i;
        if (r < M) {
            float4 v0, v1;
            v0.x = acc2[i][0] + b2v0.x; v0.y = acc2[i][1] + b2v0.y;
            v0.z = acc2[i][2] + b2v0.z; v0.w = acc2[i][3] + b2v0.w;
            v1.x = acc2[i][4] + b2v1.x; v1.y = acc2[i][5] + b2v1.y;
            v1.z = acc2[i][6] + b2v1.z; v1.w = acc2[i][7] + b2v1.w;
            *(float4*)(Z + (size_t)r * HD + tx * 8)     = v0;
            *(float4*)(Z + (size_t)r * HD + tx * 8 + 4) = v1;
        }
    }
}

// ---------------------------------------------------------------------------
__global__ __launch_bounds__(256) void zero_kernel(float* __restrict__ p, long n4)
{
    long i = (long)blockIdx.x * 256 + threadIdx.x;
    if (i < n4) ((float4*)p)[i] = make_float4(0.f, 0.f, 0.f, 0.f);
}

// z = (1 + eps[idx]) * h
__global__ __launch_bounds__(256) void scale_copy_kernel(
    const float* __restrict__ h, float* __restrict__ z,
    const float* __restrict__ epsArr, int idx, long n4)
{
    long i = (long)blockIdx.x * 256 + threadIdx.x;
    if (i >= n4) return;
    const float s = 1.0f + epsArr[idx];
    float4 v = ((const float4*)h)[i];
    v.x *= s; v.y *= s; v.z *= s; v.w *= s;
    ((float4*)z)[i] = v;
}

// z[dst[e]] += h[src[e]]  (4 edges per 256-thread block, 64 lanes/edge)
__global__ __launch_bounds__(256) void aggregate_kernel(
    const float* __restrict__ h, const int* __restrict__ src,
    const int* __restrict__ dst, float* __restrict__ z, int E)
{
    const int e = blockIdx.x * 4 + (threadIdx.x >> 6);
    const int t = threadIdx.x & 63;
    if (e >= E) return;
    const int s = src[e];
    const int d = dst[e];
    float4 v = ((const float4*)(h + (size_t)s * HD))[t];
    float* ap = z + (size_t)d * HD + t * 4;
    unsafeAtomicAdd(ap + 0, v.x);
    unsafeAtomicAdd(ap + 1, v.y);
    unsafeAtomicAdd(ap + 2, v.z);
    unsafeAtomicAdd(ap + 3, v.w);
}

// column sums / sumsq of C[N,HD] -> stats[0..HD)=sum, [HD..2HD)=sumsq
__global__ __launch_bounds__(256) void bn_stats_kernel(
    const float* __restrict__ C, float* __restrict__ stats, int Nn)
{
    constexpr int ROWS = 512;
    const int t  = threadIdx.x;
    const int r0 = blockIdx.x * ROWS;
    const int r1 = min(r0 + ROWS, Nn);
    float s = 0.f, s2 = 0.f;
    for (int r = r0; r < r1; ++r) {
        const float v = C[(size_t)r * HD + t];
        s += v; s2 += v * v;
    }
    unsafeAtomicAdd(&stats[t], s);
    unsafeAtomicAdd(&stats[HD + t], s2);
}

// h = relu(gamma * (C - mu) * rsqrt(var + eps) + beta)
__global__ __launch_bounds__(256) void bn_apply_kernel(
    const float* __restrict__ C, const float* __restrict__ stats,
    const float* __restrict__ gamma, const float* __restrict__ beta,
    float* __restrict__ hout, int Nn)
{
    const long total = (long)Nn * HD / 4;
    const long i = (long)blockIdx.x * 256 + threadIdx.x;
    if (i >= total) return;
    const int c = (int)((i * 4) % HD);
    const float invN = 1.0f / (float)Nn;
    const float4 v = ((const float4*)C)[i];
    float vv[4] = { v.x, v.y, v.z, v.w };
    float oo[4];
#pragma unroll
    for (int j = 0; j < 4; ++j) {
        const float mu  = stats[c + j] * invN;
        const float var = stats[HD + c + j] * invN - mu * mu;
        const float inv = rsqrtf(var + BN_EPS);
        const float r   = gamma[c + j] * (vv[j] - mu) * inv + beta[c + j];
        oo[j] = fmaxf(r, 0.f);
    }
    ((float4*)hout)[i] = make_float4(oo[0], oo[1], oo[2], oo[3]);
}

// pooled[batch[n]] += h[n]; counts[batch[n]] += 1
__global__ __launch_bounds__(64) void pool_kernel(
    const float* __restrict__ h, const int* __restrict__ batch,
    float* __restrict__ pooled, int* __restrict__ counts, int Nn)
{
    const int n = blockIdx.x;
    const int t = threadIdx.x;
    const int g = batch[n];
    float4 v = ((const float4*)(h + (size_t)n * HD))[t];
    float* pp = pooled + (size_t)g * HD + t * 4;
    unsafeAtomicAdd(pp + 0, v.x);
    unsafeAtomicAdd(pp + 1, v.y);
    unsafeAtomicAdd(pp + 2, v.z);
    unsafeAtomicAdd(pp + 3, v.w);
    if (t == 0) atomicAdd(&counts[g], 1);
}

// out[g] = relu(pooled[g]/cnt @ Wp1 + bp1) @ Wp2 + bp2
__global__ __launch_bounds__(128) void head_kernel(
    const float* __restrict__ pooled, const int* __restrict__ counts,
    const float* __restrict__ Wp1, const float* __restrict__ bp1,
    const float* __restrict__ Wp2, const float* __restrict__ bp2,
    float* __restrict__ out)
{
    __shared__ float red[128];
    const int g = blockIdx.x;
    const int j = threadIdx.x;
    const float inv = 1.0f / (float)max(counts[g], 1);
    const float* pr = pooled + (size_t)g * HD;
    float acc = 0.f;
    for (int k = 0; k < HD; ++k)
        acc += pr[k] * Wp1[k * (HD / 2) + j];
    const float hj = fmaxf(acc * inv + bp1[j], 0.f);
    red[j] = hj * Wp2[j];
    __syncthreads();
    for (int s = 64; s > 0; s >>= 1) {
        if (j < s) red[j] += red[j + s];
        __syncthreads();
    }
    if (j == 0) out[g] = red[0] + bp2[0];
}

// ---------------------------------------------------------------------------
extern "C" void kernel_launch(void* const* d_in, const int* in_sizes, int n_in,
                              void* d_out, int out_size, void* d_ws, size_t ws_size,
                              hipStream_t stream)
{
    const float* x     = (const float*)d_in[0];
    const int*   ei    = (const int*)  d_in[1];
    const int*   batch = (const int*)  d_in[2];
    const float* W_in  = (const float*)d_in[3];
    const float* b_in  = (const float*)d_in[4];
    const float* eps   = (const float*)d_in[5];
    const float* W1    = (const float*)d_in[6];
    const float* b1    = (const float*)d_in[7];
    const float* W2    = (const float*)d_in[8];
    const float* b2    = (const float*)d_in[9];
    const float* gamma = (const float*)d_in[10];
    const float* beta  = (const float*)d_in[11];
    const float* Wp1   = (const float*)d_in[12];
    const float* bp1   = (const float*)d_in[13];
    const float* Wp2   = (const float*)d_in[14];
    const float* bp2   = (const float*)d_in[15];

    const int* srcIdx = ei;          // edge_index[0]
    const int* dstIdx = ei + EE;     // edge_index[1]

    // workspace: h[N,H] + z[N,H] + stats + pooled + counts  (~205.3 MB)
    char* ws = (char*)d_ws;
    const size_t szH = (size_t)NN * HD * sizeof(float);   // 102.4 MB
    float* h      = (float*)ws;
    float* z      = (float*)(ws + szH);
    float* stats  = (float*)(ws + 2 * szH);
    float* pooled = stats + 2 * HD;
    int*   counts = (int*)(pooled + (size_t)NG * HD);

    const int  mTiles = (NN + 63) / 64;
    const long nh4    = (long)NN * HD / 4;
    const int  zb     = (int)((nh4 + 255) / 256);

    // input projection: h = relu(x @ W_in + b_in)
    gemm_in_kernel<<<dim3(HD / 64, mTiles), 256, 0, stream>>>(
        x, W_in, b_in, h, NN, DIN, HD);

    for (int l = 0; l < NL; ++l) {
        // z = (1+eps_l) * h ; z[dst] += h[src]
        scale_copy_kernel<<<zb, 256, 0, stream>>>(h, z, eps, l, nh4);
        aggregate_kernel<<<(EE + 3) / 4, 256, 0, stream>>>(h, srcIdx, dstIdx, z, EE);

        // z = relu(z @ W1 + b1) @ W2 + b2   (in-place, 32-row tiles)
        fused_mlp_kernel<<<(NN + 31) / 32, 256, 0, stream>>>(
            z, W1 + (size_t)l * HD * HD2, b1 + (size_t)l * HD2,
            W2 + (size_t)l * HD2 * HD, b2 + (size_t)l * HD, NN);

        // batchnorm (training stats) + relu -> h
        zero_kernel<<<1, 256, 0, stream>>>(stats, (2 * HD) / 4);
        bn_stats_kernel<<<(NN + 511) / 512, 256, 0, stream>>>(z, stats, NN);
        bn_apply_kernel<<<zb, 256, 0, stream>>>(
            z, stats, gamma + (size_t)l * HD, beta + (size_t)l * HD, h, NN);
    }

    // global mean pool + head
    zero_kernel<<<(((long)NG * HD + NG) / 4 + 255) / 256, 256, 0, stream>>>(
        pooled, ((long)NG * HD + NG) / 4);
    pool_kernel<<<NN, 64, 0, stream>>>(h, batch, pooled, counts, NN);
    head_kernel<<<NG, 128, 0, stream>>>(pooled, counts, Wp1, bp1, Wp2, bp2,
                                        (float*)d_out);
}

// Round 3
// 2036.007 us; speedup vs baseline: 5.5076x; 5.5076x over previous
//
#include <hip/hip_runtime.h>

#define NN 100000
#define NP 100096          // 782 * 128, padded row count
#define EE 300000
#define DIN 128
#define HD  256
#define HD2 512
#define NL  4
#define NG  512
#define BN_EPS 1e-5f

typedef __attribute__((ext_vector_type(8))) short s8v;      // bf16x8 frag (4 VGPRs)
typedef __attribute__((ext_vector_type(4))) float f4v;      // fp32x4 acc

typedef unsigned short ushort_t;

// float -> bf16, round-to-nearest-even
static __device__ inline ushort_t f2bf(float f) {
    unsigned u = __float_as_uint(f);
    unsigned r = (u + 0x7fffu + ((u >> 16) & 1u)) >> 16;
    return (ushort_t)r;
}
static __device__ inline float bf2f(ushort_t h) {
    return __uint_as_float(((unsigned)h) << 16);
}

// async global->LDS, 16B per lane; LDS dest = uniform base + lane*16
#define GLOAD_LDS16(g, l) __builtin_amdgcn_global_load_lds( \
    (const __attribute__((address_space(1))) unsigned int*)(const void*)(g), \
    (__attribute__((address_space(3))) unsigned int*)(void*)(l), 16, 0, 0)

// ---------------------------------------------------------------------------
// bf16 MFMA GEMM:  C[M?,ldc](bf16) = act( A[.,lda](bf16) @ BT[.,ldb]^T + bias )
// Tile 128x128, BK=64, 256 threads = 4 waves. Fragment-major LDS (conflict-free).
// Row tail handled by padded buffers (NP rows) — OOB rows compute garbage,
// stores land in pad, never read.
// ---------------------------------------------------------------------------
__global__ __launch_bounds__(256) void gemm_bf16(
    const ushort_t* __restrict__ A, int lda,
    const ushort_t* __restrict__ BT, int ldb,
    const float* __restrict__ bias,
    ushort_t* __restrict__ C, int ldc,
    int K, int doRelu)
{
    extern __shared__ char smem[];
    ushort_t* As_sh = (ushort_t*)smem;          // 16 KB: [ks(2)][mt(8)][lane(64)*8]
    ushort_t* Bs_sh = As_sh + 8192;             // 16 KB: [ks(2)][nt(8)][lane(64)*8]
    ushort_t* Cs    = As_sh;                    // epilogue reuse: 128x128 bf16 = 32 KB

    const int tid  = threadIdx.x;
    const int w    = tid >> 6;                  // wave 0..3
    const int L    = tid & 63;
    const int lm   = L & 15;                    // frag row/col
    const int q    = L >> 4;                    // quad (k-subchunk)
    const int row0 = blockIdx.x * 128;
    const int col0 = blockIdx.y * 128;

    f4v acc[2][8] = {};                         // [mt in {2w,2w+1}][nt]

    for (int k0 = 0; k0 < K; k0 += 64) {
        // stage: 16 A-instrs + 16 B-instrs, 4+4 per wave. id = ks*8 + tile.
#pragma unroll
        for (int i = 0; i < 4; ++i) {
            const int id = w * 4 + i;
            const int ks = id >> 3, tl = id & 7;
            const int kk = k0 + ks * 32 + q * 8;
            const ushort_t* ga = A  + (size_t)(row0 + tl * 16 + lm) * lda + kk;
            GLOAD_LDS16(ga, As_sh + id * 512);
            const ushort_t* gb = BT + (size_t)(col0 + tl * 16 + lm) * ldb + kk;
            GLOAD_LDS16(gb, Bs_sh + id * 512);
        }
        __syncthreads();
#pragma unroll
        for (int ks = 0; ks < 2; ++ks) {
            s8v a0 = *(const s8v*)&As_sh[(ks * 8 + 2 * w)     * 512 + L * 8];
            s8v a1 = *(const s8v*)&As_sh[(ks * 8 + 2 * w + 1) * 512 + L * 8];
#pragma unroll
            for (int nt = 0; nt < 8; ++nt) {
                s8v b = *(const s8v*)&Bs_sh[(ks * 8 + nt) * 512 + L * 8];
                acc[0][nt] = __builtin_amdgcn_mfma_f32_16x16x32_bf16(a0, b, acc[0][nt], 0, 0, 0);
                acc[1][nt] = __builtin_amdgcn_mfma_f32_16x16x32_bf16(a1, b, acc[1][nt], 0, 0, 0);
            }
        }
        __syncthreads();
    }

    // epilogue: bias + relu + cvt, via LDS for coalesced bf16 stores.
    // C/D frag: col = lm, row = q*4 + r   [measured m89/m91]
#pragma unroll
    for (int mt = 0; mt < 2; ++mt) {
#pragma unroll
        for (int nt = 0; nt < 8; ++nt) {
            const float bj = bias[col0 + nt * 16 + lm];
            f4v v = acc[mt][nt];
#pragma unroll
            for (int r = 0; r < 4; ++r) {
                float f = v[r] + bj;
                if (doRelu) f = fmaxf(f, 0.f);
                const int row = (2 * w + mt) * 16 + q * 4 + r;
                const int col = nt * 16 + lm;
                Cs[row * 128 + col] = f2bf(f);
            }
        }
    }
    __syncthreads();
#pragma unroll
    for (int i = 0; i < 8; ++i) {
        const int idx = i * 256 + tid;          // 2048 chunks of 8 bf16 (16B)
        const int row = idx >> 4, ch = idx & 15;
        s8v val = *(const s8v*)&Cs[row * 128 + ch * 8];
        *(s8v*)(C + (size_t)(row0 + row) * ldc + col0 + ch * 8) = val;
    }
}

// ---------------------------------------------------------------------------
// transpose + fp32->bf16: out[c][r] = in[r][c].  R,C multiples of 32.
__global__ __launch_bounds__(256) void transpose_cvt_kernel(
    const float* __restrict__ in, ushort_t* __restrict__ out, int R, int C)
{
    __shared__ float tile[32][33];
    const int bx = blockIdx.x * 32;   // C
    const int by = blockIdx.y * 32;   // R
    const int tx = threadIdx.x & 31;
    const int ty = threadIdx.x >> 5;  // 0..7
#pragma unroll
    for (int i = 0; i < 32; i += 8)
        tile[ty + i][tx] = in[(size_t)(by + ty + i) * C + bx + tx];
    __syncthreads();
#pragma unroll
    for (int i = 0; i < 32; i += 8)
        out[(size_t)(bx + ty + i) * R + by + tx] = f2bf(tile[tx][ty + i]);
}

// fp32 -> bf16 elementwise (x conversion), 4 elems/thread
__global__ __launch_bounds__(256) void cvt_kernel(
    const float* __restrict__ in, ushort_t* __restrict__ out, long n4)
{
    const long i = (long)blockIdx.x * 256 + threadIdx.x;
    if (i >= n4) return;
    const float4 v = ((const float4*)in)[i];
    ushort4 o;
    o.x = f2bf(v.x); o.y = f2bf(v.y); o.z = f2bf(v.z); o.w = f2bf(v.w);
    ((ushort4*)out)[i] = o;
}

__global__ __launch_bounds__(256) void zero_kernel(float* __restrict__ p, long n4)
{
    const long i = (long)blockIdx.x * 256 + threadIdx.x;
    if (i < n4) ((float4*)p)[i] = make_float4(0.f, 0.f, 0.f, 0.f);
}

// ---------------- CSR build (per call; edges are layer-invariant) -----------
__global__ __launch_bounds__(256) void hist_kernel(
    const int* __restrict__ dst, int* __restrict__ deg, int E)
{
    const int e = blockIdx.x * 256 + threadIdx.x;
    if (e < E) atomicAdd(&deg[dst[e]], 1);
}

// per-block exclusive scan + block sums
__global__ __launch_bounds__(256) void scan1_kernel(
    const int* __restrict__ deg, int* __restrict__ partial,
    int* __restrict__ bsums, int n)
{
    __shared__ int tmp[256];
    const int i = blockIdx.x * 256 + threadIdx.x;
    const int v = (i < n) ? deg[i] : 0;
    tmp[threadIdx.x] = v;
    __syncthreads();
    for (int off = 1; off < 256; off <<= 1) {
        const int t = (threadIdx.x >= off) ? tmp[threadIdx.x - off] : 0;
        __syncthreads();
        tmp[threadIdx.x] += t;
        __syncthreads();
    }
    if (i < n) partial[i] = tmp[threadIdx.x] - v;
    if (threadIdx.x == 255) bsums[blockIdx.x] = tmp[255];
}

// exclusive scan of block sums (nb <= 512), in place
__global__ __launch_bounds__(512) void scan2_kernel(int* __restrict__ bsums, int nb)
{
    __shared__ int tmp[512];
    const int i = threadIdx.x;
    const int v = (i < nb) ? bsums[i] : 0;
    tmp[i] = v;
    __syncthreads();
    for (int off = 1; off < 512; off <<= 1) {
        const int t = (i >= off) ? tmp[i - off] : 0;
        __syncthreads();
        tmp[i] += t;
        __syncthreads();
    }
    if (i < nb) bsums[i] = tmp[i] - v;
}

__global__ __launch_bounds__(256) void scan3_kernel(
    const int* __restrict__ partial, const int* __restrict__ bsums,
    int* __restrict__ offs, int* __restrict__ cursor, int n)
{
    const int i = blockIdx.x * 256 + threadIdx.x;
    if (i < n) {
        const int o = partial[i] + bsums[blockIdx.x];
        offs[i] = o;
        cursor[i] = o;
    }
}

__global__ __launch_bounds__(256) void scatter_kernel(
    const int* __restrict__ src, const int* __restrict__ dst,
    int* __restrict__ cursor, int* __restrict__ srcSorted, int E)
{
    const int e = blockIdx.x * 256 + threadIdx.x;
    if (e >= E) return;
    const int p = atomicAdd(&cursor[dst[e]], 1);
    srcSorted[p] = src[e];
}

// ---------------------------------------------------------------------------
// z[n] = bf16( (1+eps)*h[n] + sum_{s in nbrs(n)} h[s] ), fp32 accumulate.
// One wave per node, lane t handles cols 4t..4t+3 (8B each).
__global__ __launch_bounds__(256) void aggregate_kernel(
    const ushort_t* __restrict__ h, const int* __restrict__ offs,
    const int* __restrict__ deg, const int* __restrict__ srcSorted,
    const float* __restrict__ epsArr, int epsIdx,
    ushort_t* __restrict__ z)
{
    const int n = blockIdx.x * 4 + (threadIdx.x >> 6);
    const int t = threadIdx.x & 63;
    const int start = offs[n];
    const int dc = deg[n];
    float a0 = 0.f, a1 = 0.f, a2 = 0.f, a3 = 0.f;
    for (int j = 0; j < dc; ++j) {
        const int s = srcSorted[start + j];
        const ushort4 u = *(const ushort4*)(h + (size_t)s * HD + t * 4);
        a0 += bf2f(u.x); a1 += bf2f(u.y); a2 += bf2f(u.z); a3 += bf2f(u.w);
    }
    const float sc = 1.0f + epsArr[epsIdx];
    const ushort4 hs = *(const ushort4*)(h + (size_t)n * HD + t * 4);
    ushort4 o;
    o.x = f2bf(sc * bf2f(hs.x) + a0);
    o.y = f2bf(sc * bf2f(hs.y) + a1);
    o.z = f2bf(sc * bf2f(hs.z) + a2);
    o.w = f2bf(sc * bf2f(hs.w) + a3);
    *(ushort4*)(z + (size_t)n * HD + t * 4) = o;
}

// column sums / sumsq of z[N,HD] (bf16) -> stats fp32
__global__ __launch_bounds__(256) void bn_stats_kernel(
    const ushort_t* __restrict__ z, float* __restrict__ stats, int Nn)
{
    constexpr int ROWS = 512;
    const int t  = threadIdx.x;
    const int r0 = blockIdx.x * ROWS;
    const int r1 = min(r0 + ROWS, Nn);
    float s = 0.f, s2 = 0.f;
    for (int r = r0; r < r1; ++r) {
        const float v = bf2f(z[(size_t)r * HD + t]);
        s += v; s2 += v * v;
    }
    unsafeAtomicAdd(&stats[t], s);
    unsafeAtomicAdd(&stats[HD + t], s2);
}

// h = bf16( relu(gamma * (z - mu) * rsqrt(var+eps) + beta) ), 8 cols/thread
__global__ __launch_bounds__(256) void bn_apply_kernel(
    const ushort_t* __restrict__ z, const float* __restrict__ stats,
    const float* __restrict__ gamma, const float* __restrict__ beta,
    ushort_t* __restrict__ hout, int Nn)
{
    const long total = (long)Nn * HD / 8;
    const long i = (long)blockIdx.x * 256 + threadIdx.x;
    if (i >= total) return;
    const int c = (int)((i * 8) % HD);
    const float invN = 1.0f / (float)Nn;
    ushort_t vin[8], vout[8];
    *(ushort4*)&vin[0] = ((const ushort4*)z)[i * 2];
    *(ushort4*)&vin[4] = ((const ushort4*)z)[i * 2 + 1];
#pragma unroll
    for (int j = 0; j < 8; ++j) {
        const float mu  = stats[c + j] * invN;
        const float var = stats[HD + c + j] * invN - mu * mu;
        const float inv = rsqrtf(var + BN_EPS);
        const float r   = gamma[c + j] * (bf2f(vin[j]) - mu) * inv + beta[c + j];
        vout[j] = f2bf(fmaxf(r, 0.f));
    }
    ((ushort4*)hout)[i * 2]     = *(ushort4*)&vout[0];
    ((ushort4*)hout)[i * 2 + 1] = *(ushort4*)&vout[4];
}

// pooled[batch[n]] += h[n] (fp32 atomics); counts[batch[n]] += 1
__global__ __launch_bounds__(256) void pool_kernel(
    const ushort_t* __restrict__ h, const int* __restrict__ batch,
    float* __restrict__ pooled, int* __restrict__ counts)
{
    const int n = blockIdx.x * 4 + (threadIdx.x >> 6);
    const int t = threadIdx.x & 63;
    const int g = batch[n];
    const ushort4 u = *(const ushort4*)(h + (size_t)n * HD + t * 4);
    float* pp = pooled + (size_t)g * HD + t * 4;
    unsafeAtomicAdd(pp + 0, bf2f(u.x));
    unsafeAtomicAdd(pp + 1, bf2f(u.y));
    unsafeAtomicAdd(pp + 2, bf2f(u.z));
    unsafeAtomicAdd(pp + 3, bf2f(u.w));
    if (t == 0) atomicAdd(&counts[g], 1);
}

__global__ __launch_bounds__(128) void head_kernel(
    const float* __restrict__ pooled, const int* __restrict__ counts,
    const float* __restrict__ Wp1, const float* __restrict__ bp1,
    const float* __restrict__ Wp2, const float* __restrict__ bp2,
    float* __restrict__ out)
{
    __shared__ float red[128];
    const int g = blockIdx.x;
    const int j = threadIdx.x;
    const float inv = 1.0f / (float)max(counts[g], 1);
    const float* pr = pooled + (size_t)g * HD;
    float acc = 0.f;
    for (int k = 0; k < HD; ++k)
        acc += pr[k] * Wp1[k * (HD / 2) + j];
    const float hj = fmaxf(acc * inv + bp1[j], 0.f);
    red[j] = hj * Wp2[j];
    __syncthreads();
    for (int s = 64; s > 0; s >>= 1) {
        if (j < s) red[j] += red[j + s];
        __syncthreads();
    }
    if (j == 0) out[g] = red[0] + bp2[0];
}

// ---------------------------------------------------------------------------
extern "C" void kernel_launch(void* const* d_in, const int* in_sizes, int n_in,
                              void* d_out, int out_size, void* d_ws, size_t ws_size,
                              hipStream_t stream)
{
    const float* x     = (const float*)d_in[0];
    const int*   ei    = (const int*)  d_in[1];
    const int*   batch = (const int*)  d_in[2];
    const float* W_in  = (const float*)d_in[3];
    const float* b_in  = (const float*)d_in[4];
    const float* eps   = (const float*)d_in[5];
    const float* W1    = (const float*)d_in[6];
    const float* b1    = (const float*)d_in[7];
    const float* W2    = (const float*)d_in[8];
    const float* b2    = (const float*)d_in[9];
    const float* gamma = (const float*)d_in[10];
    const float* beta  = (const float*)d_in[11];
    const float* Wp1   = (const float*)d_in[12];
    const float* bp1   = (const float*)d_in[13];
    const float* Wp2   = (const float*)d_in[14];
    const float* bp2   = (const float*)d_in[15];

    const int* srcIdx = ei;
    const int* dstIdx = ei + EE;

    // ---- workspace layout (~210 MB) ----
    char* p = (char*)d_ws;
    ushort_t* h       = (ushort_t*)p;  p += (size_t)NP * HD  * 2;   // 51.2 MB
    ushort_t* z       = (ushort_t*)p;  p += (size_t)NP * HD  * 2;   // 51.2 MB
    ushort_t* hidden  = (ushort_t*)p;  p += (size_t)NP * HD2 * 2;   // 102.5 MB (x_bf16 alias)
    ushort_t* W1T     = (ushort_t*)p;  p += (size_t)NL * HD2 * HD * 2;
    ushort_t* W2T     = (ushort_t*)p;  p += (size_t)NL * HD * HD2 * 2;
    ushort_t* WinT    = (ushort_t*)p;  p += (size_t)HD * DIN * 2;
    int* deg          = (int*)p;       p += (size_t)NN * 4;
    int* partial      = (int*)p;       p += (size_t)NN * 4;
    int* bsums        = (int*)p;       p += 512 * 4;
    int* offs         = (int*)p;       p += (size_t)NN * 4;
    int* cursor       = (int*)p;       p += (size_t)NN * 4;
    int* srcSorted    = (int*)p;       p += (size_t)EE * 4;
    float* stats      = (float*)p;     p += 2 * HD * 4;
    float* pooled     = (float*)p;     p += (size_t)NG * HD * 4;
    int* counts       = (int*)p;       p += NG * 4;
    ushort_t* x_bf    = hidden;        // GEMM0 A; clobbered later by GEMM1 out

    const int nb  = (NN + 255) / 256;          // 391
    const dim3 rowsGrid(NP / 128, 1);

    // ---- weight conversion (bf16, transposed) ----
    transpose_cvt_kernel<<<dim3(HD / 32, DIN / 32), 256, 0, stream>>>(W_in, WinT, DIN, HD);
    for (int l = 0; l < NL; ++l) {
        transpose_cvt_kernel<<<dim3(HD2 / 32, HD / 32), 256, 0, stream>>>(
            W1 + (size_t)l * HD * HD2, W1T + (size_t)l * HD2 * HD, HD, HD2);
        transpose_cvt_kernel<<<dim3(HD / 32, HD2 / 32), 256, 0, stream>>>(
            W2 + (size_t)l * HD2 * HD, W2T + (size_t)l * HD * HD2, HD2, HD);
    }
    // x -> bf16
    cvt_kernel<<<(int)(((long)NN * DIN / 4 + 255) / 256), 256, 0, stream>>>(
        x, x_bf, (long)NN * DIN / 4);

    // ---- CSR build (once; edges layer-invariant) ----
    zero_kernel<<<(NN / 4 + 255) / 256, 256, 0, stream>>>((float*)deg, NN / 4);
    hist_kernel<<<(EE + 255) / 256, 256, 0, stream>>>(dstIdx, deg, EE);
    scan1_kernel<<<nb, 256, 0, stream>>>(deg, partial, bsums, NN);
    scan2_kernel<<<1, 512, 0, stream>>>(bsums, nb);
    scan3_kernel<<<nb, 256, 0, stream>>>(partial, bsums, offs, cursor, NN);
    scatter_kernel<<<(EE + 255) / 256, 256, 0, stream>>>(srcIdx, dstIdx, cursor, srcSorted, EE);

    // ---- input projection: h = relu(x @ W_in + b_in) ----
    gemm_bf16<<<dim3(NP / 128, HD / 128), 256, 32768, stream>>>(
        x_bf, DIN, WinT, DIN, b_in, h, HD, DIN, 1);

    // ---- GIN layers ----
    for (int l = 0; l < NL; ++l) {
        aggregate_kernel<<<NN / 4, 256, 0, stream>>>(
            h, offs, deg, srcSorted, eps, l, z);

        // hidden = relu(z @ W1 + b1)
        gemm_bf16<<<dim3(NP / 128, HD2 / 128), 256, 32768, stream>>>(
            z, HD, W1T + (size_t)l * HD2 * HD, HD,
            b1 + (size_t)l * HD2, hidden, HD2, HD, 1);

        // z = hidden @ W2 + b2
        gemm_bf16<<<dim3(NP / 128, HD / 128), 256, 32768, stream>>>(
            hidden, HD2, W2T + (size_t)l * HD * HD2, HD2,
            b2 + (size_t)l * HD, z, HD, HD2, 0);

        // batchnorm + relu -> h
        zero_kernel<<<1, 256, 0, stream>>>(stats, (2 * HD) / 4);
        bn_stats_kernel<<<(NN + 511) / 512, 256, 0, stream>>>(z, stats, NN);
        bn_apply_kernel<<<(int)(((long)NN * HD / 8 + 255) / 256), 256, 0, stream>>>(
            z, stats, gamma + (size_t)l * HD, beta + (size_t)l * HD, h, NN);
    }

    // ---- global mean pool + head ----
    zero_kernel<<<(int)((((long)NG * HD + NG) / 4 + 255) / 256), 256, 0, stream>>>(
        pooled, ((long)NG * HD + NG) / 4);
    pool_kernel<<<NN / 4, 256, 0, stream>>>(h, batch, pooled, counts);
    head_kernel<<<NG, 128, 0, stream>>>(pooled, counts, Wp1, bp1, Wp2, bp2,
                                        (float*)d_out);
}

// Round 4
// 1652.300 us; speedup vs baseline: 6.7865x; 1.2322x over previous
//
#include <hip/hip_runtime.h>

#define NN 100000
#define NP 100096          // 782 * 128, padded row count
#define EE 300000
#define DIN 128
#define HD  256
#define HD2 512
#define NL  4
#define NG  512
#define BN_EPS 1e-5f

typedef __attribute__((ext_vector_type(8))) short s8v;      // bf16x8 frag (4 VGPRs)
typedef __attribute__((ext_vector_type(4))) float f4v;      // fp32x4 acc

typedef unsigned short ushort_t;

// float -> bf16, round-to-nearest-even
static __device__ inline ushort_t f2bf(float f) {
    unsigned u = __float_as_uint(f);
    unsigned r = (u + 0x7fffu + ((u >> 16) & 1u)) >> 16;
    return (ushort_t)r;
}
static __device__ inline float bf2f(ushort_t h) {
    return __uint_as_float(((unsigned)h) << 16);
}

// async global->LDS, 16B per lane; LDS dest = uniform base + lane*16
#define GLOAD_LDS16(g, l) __builtin_amdgcn_global_load_lds( \
    (const __attribute__((address_space(1))) unsigned int*)(const void*)(g), \
    (__attribute__((address_space(3))) unsigned int*)(void*)(l), 16, 0, 0)

// ---------------------------------------------------------------------------
// bf16 MFMA GEMM:  C[M?,ldc](bf16) = act( A[.,lda](bf16) @ BT[.,ldb]^T + bias )
// Tile 128x128, BK=64, 256 threads = 4 waves. Fragment-major LDS (conflict-free).
// ---------------------------------------------------------------------------
__global__ __launch_bounds__(256) void gemm_bf16(
    const ushort_t* __restrict__ A, int lda,
    const ushort_t* __restrict__ BT, int ldb,
    const float* __restrict__ bias,
    ushort_t* __restrict__ C, int ldc,
    int K, int doRelu)
{
    extern __shared__ char smem[];
    ushort_t* As_sh = (ushort_t*)smem;          // 16 KB
    ushort_t* Bs_sh = As_sh + 8192;             // 16 KB
    ushort_t* Cs    = As_sh;                    // epilogue reuse: 128x128 bf16

    const int tid  = threadIdx.x;
    const int w    = tid >> 6;
    const int L    = tid & 63;
    const int lm   = L & 15;
    const int q    = L >> 4;
    const int row0 = blockIdx.x * 128;
    const int col0 = blockIdx.y * 128;

    f4v acc[2][8] = {};

    for (int k0 = 0; k0 < K; k0 += 64) {
#pragma unroll
        for (int i = 0; i < 4; ++i) {
            const int id = w * 4 + i;
            const int ks = id >> 3, tl = id & 7;
            const int kk = k0 + ks * 32 + q * 8;
            const ushort_t* ga = A  + (size_t)(row0 + tl * 16 + lm) * lda + kk;
            GLOAD_LDS16(ga, As_sh + id * 512);
            const ushort_t* gb = BT + (size_t)(col0 + tl * 16 + lm) * ldb + kk;
            GLOAD_LDS16(gb, Bs_sh + id * 512);
        }
        __syncthreads();
#pragma unroll
        for (int ks = 0; ks < 2; ++ks) {
            s8v a0 = *(const s8v*)&As_sh[(ks * 8 + 2 * w)     * 512 + L * 8];
            s8v a1 = *(const s8v*)&As_sh[(ks * 8 + 2 * w + 1) * 512 + L * 8];
#pragma unroll
            for (int nt = 0; nt < 8; ++nt) {
                s8v b = *(const s8v*)&Bs_sh[(ks * 8 + nt) * 512 + L * 8];
                acc[0][nt] = __builtin_amdgcn_mfma_f32_16x16x32_bf16(a0, b, acc[0][nt], 0, 0, 0);
                acc[1][nt] = __builtin_amdgcn_mfma_f32_16x16x32_bf16(a1, b, acc[1][nt], 0, 0, 0);
            }
        }
        __syncthreads();
    }

    // epilogue: bias + relu + cvt; C/D frag: col = lm, row = q*4 + r
#pragma unroll
    for (int mt = 0; mt < 2; ++mt) {
#pragma unroll
        for (int nt = 0; nt < 8; ++nt) {
            const float bj = bias[col0 + nt * 16 + lm];
            f4v v = acc[mt][nt];
#pragma unroll
            for (int r = 0; r < 4; ++r) {
                float f = v[r] + bj;
                if (doRelu) f = fmaxf(f, 0.f);
                const int row = (2 * w + mt) * 16 + q * 4 + r;
                const int col = nt * 16 + lm;
                Cs[row * 128 + col] = f2bf(f);
            }
        }
    }
    __syncthreads();
#pragma unroll
    for (int i = 0; i < 8; ++i) {
        const int idx = i * 256 + tid;
        const int row = idx >> 4, ch = idx & 15;
        s8v val = *(const s8v*)&Cs[row * 128 + ch * 8];
        *(s8v*)(C + (size_t)(row0 + row) * ldc + col0 + ch * 8) = val;
    }
}

// ---------------------------------------------------------------------------
__global__ __launch_bounds__(256) void transpose_cvt_kernel(
    const float* __restrict__ in, ushort_t* __restrict__ out, int R, int C)
{
    __shared__ float tile[32][33];
    const int bx = blockIdx.x * 32;
    const int by = blockIdx.y * 32;
    const int tx = threadIdx.x & 31;
    const int ty = threadIdx.x >> 5;
#pragma unroll
    for (int i = 0; i < 32; i += 8)
        tile[ty + i][tx] = in[(size_t)(by + ty + i) * C + bx + tx];
    __syncthreads();
#pragma unroll
    for (int i = 0; i < 32; i += 8)
        out[(size_t)(bx + ty + i) * R + by + tx] = f2bf(tile[tx][ty + i]);
}

__global__ __launch_bounds__(256) void cvt_kernel(
    const float* __restrict__ in, ushort_t* __restrict__ out, long n4)
{
    const long i = (long)blockIdx.x * 256 + threadIdx.x;
    if (i >= n4) return;
    const float4 v = ((const float4*)in)[i];
    ushort4 o;
    o.x = f2bf(v.x); o.y = f2bf(v.y); o.z = f2bf(v.z); o.w = f2bf(v.w);
    ((ushort4*)out)[i] = o;
}

__global__ __launch_bounds__(256) void zero_kernel(float* __restrict__ p, long n4)
{
    const long i = (long)blockIdx.x * 256 + threadIdx.x;
    if (i < n4) ((float4*)p)[i] = make_float4(0.f, 0.f, 0.f, 0.f);
}

// ---------------- CSR build (per call; edges are layer-invariant) -----------
__global__ __launch_bounds__(256) void hist_kernel(
    const int* __restrict__ dst, int* __restrict__ deg, int E)
{
    const int e = blockIdx.x * 256 + threadIdx.x;
    if (e < E) atomicAdd(&deg[dst[e]], 1);
}

__global__ __launch_bounds__(256) void scan1_kernel(
    const int* __restrict__ deg, int* __restrict__ partial,
    int* __restrict__ bsums, int n)
{
    __shared__ int tmp[256];
    const int i = blockIdx.x * 256 + threadIdx.x;
    const int v = (i < n) ? deg[i] : 0;
    tmp[threadIdx.x] = v;
    __syncthreads();
    for (int off = 1; off < 256; off <<= 1) {
        const int t = (threadIdx.x >= off) ? tmp[threadIdx.x - off] : 0;
        __syncthreads();
        tmp[threadIdx.x] += t;
        __syncthreads();
    }
    if (i < n) partial[i] = tmp[threadIdx.x] - v;
    if (threadIdx.x == 255) bsums[blockIdx.x] = tmp[255];
}

__global__ __launch_bounds__(512) void scan2_kernel(int* __restrict__ bsums, int nb)
{
    __shared__ int tmp[512];
    const int i = threadIdx.x;
    const int v = (i < nb) ? bsums[i] : 0;
    tmp[i] = v;
    __syncthreads();
    for (int off = 1; off < 512; off <<= 1) {
        const int t = (i >= off) ? tmp[i - off] : 0;
        __syncthreads();
        tmp[i] += t;
        __syncthreads();
    }
    if (i < nb) bsums[i] = tmp[i] - v;
}

__global__ __launch_bounds__(256) void scan3_kernel(
    const int* __restrict__ partial, const int* __restrict__ bsums,
    int* __restrict__ offs, int* __restrict__ cursor, int n)
{
    const int i = blockIdx.x * 256 + threadIdx.x;
    if (i < n) {
        const int o = partial[i] + bsums[blockIdx.x];
        offs[i] = o;
        cursor[i] = o;
    }
}

__global__ __launch_bounds__(256) void scatter_kernel(
    const int* __restrict__ src, const int* __restrict__ dst,
    int* __restrict__ cursor, int* __restrict__ srcSorted, int E)
{
    const int e = blockIdx.x * 256 + threadIdx.x;
    if (e >= E) return;
    const int p = atomicAdd(&cursor[dst[e]], 1);
    srcSorted[p] = src[e];
}

// ---------------------------------------------------------------------------
// z[n] = bf16( (1+eps)*h[n] + sum_{s in nbrs(n)} h[s] ), fp32 accumulate.
__global__ __launch_bounds__(256) void aggregate_kernel(
    const ushort_t* __restrict__ h, const int* __restrict__ offs,
    const int* __restrict__ deg, const int* __restrict__ srcSorted,
    const float* __restrict__ epsArr, int epsIdx,
    ushort_t* __restrict__ z)
{
    const int n = blockIdx.x * 4 + (threadIdx.x >> 6);
    const int t = threadIdx.x & 63;
    const int start = offs[n];
    const int dc = deg[n];
    float a0 = 0.f, a1 = 0.f, a2 = 0.f, a3 = 0.f;
    for (int j = 0; j < dc; ++j) {
        const int s = srcSorted[start + j];
        const ushort4 u = *(const ushort4*)(h + (size_t)s * HD + t * 4);
        a0 += bf2f(u.x); a1 += bf2f(u.y); a2 += bf2f(u.z); a3 += bf2f(u.w);
    }
    const float sc = 1.0f + epsArr[epsIdx];
    const ushort4 hs = *(const ushort4*)(h + (size_t)n * HD + t * 4);
    ushort4 o;
    o.x = f2bf(sc * bf2f(hs.x) + a0);
    o.y = f2bf(sc * bf2f(hs.y) + a1);
    o.z = f2bf(sc * bf2f(hs.z) + a2);
    o.w = f2bf(sc * bf2f(hs.w) + a3);
    *(ushort4*)(z + (size_t)n * HD + t * 4) = o;
}

// column sums / sumsq of z[N,HD] (bf16) -> stats fp32
__global__ __launch_bounds__(256) void bn_stats_kernel(
    const ushort_t* __restrict__ z, float* __restrict__ stats, int Nn)
{
    constexpr int ROWS = 512;
    const int t  = threadIdx.x;
    const int r0 = blockIdx.x * ROWS;
    const int r1 = min(r0 + ROWS, Nn);
    float s = 0.f, s2 = 0.f;
    for (int r = r0; r < r1; ++r) {
        const float v = bf2f(z[(size_t)r * HD + t]);
        s += v; s2 += v * v;
    }
    unsafeAtomicAdd(&stats[t], s);
    unsafeAtomicAdd(&stats[HD + t], s2);
}

// h = bf16( relu(gamma * (z - mu) * rsqrt(var+eps) + beta) )
__global__ __launch_bounds__(256) void bn_apply_kernel(
    const ushort_t* __restrict__ z, const float* __restrict__ stats,
    const float* __restrict__ gamma, const float* __restrict__ beta,
    ushort_t* __restrict__ hout, int Nn)
{
    const long total = (long)Nn * HD / 8;
    const long i = (long)blockIdx.x * 256 + threadIdx.x;
    if (i >= total) return;
    const int c = (int)((i * 8) % HD);
    const float invN = 1.0f / (float)Nn;
    ushort_t vin[8], vout[8];
    *(ushort4*)&vin[0] = ((const ushort4*)z)[i * 2];
    *(ushort4*)&vin[4] = ((const ushort4*)z)[i * 2 + 1];
#pragma unroll
    for (int j = 0; j < 8; ++j) {
        const float mu  = stats[c + j] * invN;
        const float var = stats[HD + c + j] * invN - mu * mu;
        const float inv = rsqrtf(var + BN_EPS);
        const float r   = gamma[c + j] * (bf2f(vin[j]) - mu) * inv + beta[c + j];
        vout[j] = f2bf(fmaxf(r, 0.f));
    }
    ((ushort4*)hout)[i * 2]     = *(ushort4*)&vout[0];
    ((ushort4*)hout)[i * 2 + 1] = *(ushort4*)&vout[4];
}

// ---------------------------------------------------------------------------
// Fused mean-pool + head. batch is SORTED: block g binary-searches its node
// range [start,end), accumulates column means in registers/LDS (no atomics),
// then computes relu(mean @ Wp1 + bp1) @ Wp2 + bp2 in-block.
__global__ __launch_bounds__(256) void pool_head_kernel(
    const ushort_t* __restrict__ h, const int* __restrict__ batch,
    const float* __restrict__ Wp1, const float* __restrict__ bp1,
    const float* __restrict__ Wp2, const float* __restrict__ bp2,
    float* __restrict__ out)
{
    __shared__ float pool[HD];
    __shared__ float red[128];
    __shared__ int seg[2];
    const int g = blockIdx.x;
    const int t = threadIdx.x;
    if (t == 0) {
        int lo = 0, hi = NN;
        while (lo < hi) { const int m = (lo + hi) >> 1; if (batch[m] < g) lo = m + 1; else hi = m; }
        seg[0] = lo;
        hi = NN;
        while (lo < hi) { const int m = (lo + hi) >> 1; if (batch[m] < g + 1) lo = m + 1; else hi = m; }
        seg[1] = lo;
    }
    __syncthreads();
    const int start = seg[0], end = seg[1];
    float s = 0.f;
    for (int r = start; r < end; ++r)
        s += bf2f(h[(size_t)r * HD + t]);
    pool[t] = s * (1.0f / (float)max(end - start, 1));
    __syncthreads();
    if (t < 128) {
        float acc = 0.f;
#pragma unroll 4
        for (int k = 0; k < HD; ++k)
            acc += pool[k] * Wp1[k * 128 + t];
        red[t] = fmaxf(acc + bp1[t], 0.f) * Wp2[t];
    }
    __syncthreads();
    for (int sft = 64; sft > 0; sft >>= 1) {
        if (t < sft) red[t] += red[t + sft];
        __syncthreads();
    }
    if (t == 0) out[g] = red[0] + bp2[0];
}

// ---------------------------------------------------------------------------
extern "C" void kernel_launch(void* const* d_in, const int* in_sizes, int n_in,
                              void* d_out, int out_size, void* d_ws, size_t ws_size,
                              hipStream_t stream)
{
    const float* x     = (const float*)d_in[0];
    const int*   ei    = (const int*)  d_in[1];
    const int*   batch = (const int*)  d_in[2];
    const float* W_in  = (const float*)d_in[3];
    const float* b_in  = (const float*)d_in[4];
    const float* eps   = (const float*)d_in[5];
    const float* W1    = (const float*)d_in[6];
    const float* b1    = (const float*)d_in[7];
    const float* W2    = (const float*)d_in[8];
    const float* b2    = (const float*)d_in[9];
    const float* gamma = (const float*)d_in[10];
    const float* beta  = (const float*)d_in[11];
    const float* Wp1   = (const float*)d_in[12];
    const float* bp1   = (const float*)d_in[13];
    const float* Wp2   = (const float*)d_in[14];
    const float* bp2   = (const float*)d_in[15];

    const int* srcIdx = ei;
    const int* dstIdx = ei + EE;

    // ---- workspace layout ----
    char* p = (char*)d_ws;
    ushort_t* h       = (ushort_t*)p;  p += (size_t)NP * HD  * 2;
    ushort_t* z       = (ushort_t*)p;  p += (size_t)NP * HD  * 2;
    ushort_t* hidden  = (ushort_t*)p;  p += (size_t)NP * HD2 * 2;
    ushort_t* W1T     = (ushort_t*)p;  p += (size_t)NL * HD2 * HD * 2;
    ushort_t* W2T     = (ushort_t*)p;  p += (size_t)NL * HD * HD2 * 2;
    ushort_t* WinT    = (ushort_t*)p;  p += (size_t)HD * DIN * 2;
    int* deg          = (int*)p;       p += (size_t)NN * 4;
    int* partial      = (int*)p;       p += (size_t)NN * 4;
    int* bsums        = (int*)p;       p += 512 * 4;
    int* offs         = (int*)p;       p += (size_t)NN * 4;
    int* cursor       = (int*)p;       p += (size_t)NN * 4;
    int* srcSorted    = (int*)p;       p += (size_t)EE * 4;
    float* stats      = (float*)p;     p += 2 * HD * 4;
    ushort_t* x_bf    = hidden;        // GEMM0 A; clobbered later by GEMM1 out

    const int nb = (NN + 255) / 256;   // 391

    // ---- weight conversion (bf16, transposed) ----
    transpose_cvt_kernel<<<dim3(HD / 32, DIN / 32), 256, 0, stream>>>(W_in, WinT, DIN, HD);
    for (int l = 0; l < NL; ++l) {
        transpose_cvt_kernel<<<dim3(HD2 / 32, HD / 32), 256, 0, stream>>>(
            W1 + (size_t)l * HD * HD2, W1T + (size_t)l * HD2 * HD, HD, HD2);
        transpose_cvt_kernel<<<dim3(HD / 32, HD2 / 32), 256, 0, stream>>>(
            W2 + (size_t)l * HD2 * HD, W2T + (size_t)l * HD * HD2, HD2, HD);
    }
    cvt_kernel<<<(int)(((long)NN * DIN / 4 + 255) / 256), 256, 0, stream>>>(
        x, x_bf, (long)NN * DIN / 4);

    // ---- CSR build (once; edges layer-invariant) ----
    zero_kernel<<<(NN / 4 + 255) / 256, 256, 0, stream>>>((float*)deg, NN / 4);
    hist_kernel<<<(EE + 255) / 256, 256, 0, stream>>>(dstIdx, deg, EE);
    scan1_kernel<<<nb, 256, 0, stream>>>(deg, partial, bsums, NN);
    scan2_kernel<<<1, 512, 0, stream>>>(bsums, nb);
    scan3_kernel<<<nb, 256, 0, stream>>>(partial, bsums, offs, cursor, NN);
    scatter_kernel<<<(EE + 255) / 256, 256, 0, stream>>>(srcIdx, dstIdx, cursor, srcSorted, EE);

    // ---- input projection: h = relu(x @ W_in + b_in) ----
    gemm_bf16<<<dim3(NP / 128, HD / 128), 256, 32768, stream>>>(
        x_bf, DIN, WinT, DIN, b_in, h, HD, DIN, 1);

    // ---- GIN layers ----
    for (int l = 0; l < NL; ++l) {
        aggregate_kernel<<<NN / 4, 256, 0, stream>>>(
            h, offs, deg, srcSorted, eps, l, z);

        gemm_bf16<<<dim3(NP / 128, HD2 / 128), 256, 32768, stream>>>(
            z, HD, W1T + (size_t)l * HD2 * HD, HD,
            b1 + (size_t)l * HD2, hidden, HD2, HD, 1);

        gemm_bf16<<<dim3(NP / 128, HD / 128), 256, 32768, stream>>>(
            hidden, HD2, W2T + (size_t)l * HD * HD2, HD2,
            b2 + (size_t)l * HD, z, HD, HD2, 0);

        zero_kernel<<<1, 256, 0, stream>>>(stats, (2 * HD) / 4);
        bn_stats_kernel<<<(NN + 511) / 512, 256, 0, stream>>>(z, stats, NN);
        bn_apply_kernel<<<(int)(((long)NN * HD / 8 + 255) / 256), 256, 0, stream>>>(
            z, stats, gamma + (size_t)l * HD, beta + (size_t)l * HD, h, NN);
    }

    // ---- fused mean pool + head (batch sorted -> binary-searched segments) ----
    pool_head_kernel<<<NG, 256, 0, stream>>>(h, batch, Wp1, bp1, Wp2, bp2,
                                             (float*)d_out);
}

// Round 5
// 1223.480 us; speedup vs baseline: 9.1652x; 1.3505x over previous
//
#include <hip/hip_runtime.h>

#define NN 100000
#define NP 100096          // 782 * 128, padded row count
#define EE 300000
#define DIN 128
#define HD  256
#define HD2 512
#define NL  4
#define NG  512
#define BN_EPS 1e-5f

typedef __attribute__((ext_vector_type(8))) short s8v;      // bf16x8 frag (4 VGPRs)
typedef __attribute__((ext_vector_type(4))) float f4v;      // fp32x4 acc

typedef unsigned short ushort_t;

// float -> bf16, round-to-nearest-even
static __device__ inline ushort_t f2bf(float f) {
    unsigned u = __float_as_uint(f);
    unsigned r = (u + 0x7fffu + ((u >> 16) & 1u)) >> 16;
    return (ushort_t)r;
}
static __device__ inline float bf2f(ushort_t h) {
    return __uint_as_float(((unsigned)h) << 16);
}

// async global->LDS, 16B per lane; LDS dest = uniform base + lane*16
#define GLOAD_LDS16(g, l) __builtin_amdgcn_global_load_lds( \
    (const __attribute__((address_space(1))) unsigned int*)(const void*)(g), \
    (__attribute__((address_space(3))) unsigned int*)(void*)(l), 16, 0, 0)

// ---------------------------------------------------------------------------
// bf16 MFMA GEMM:  C[.,ldc](bf16) = act( A[.,lda](bf16) @ BT[.,ldb]^T + bias )
// Tile 128x128, BK=64, 256 threads = 4 waves. Fragment-major LDS (conflict-free).
// doStats: additionally accumulate column sum/sumsq of the (pre-bf16) output
// into stats[0..HD) / stats[HD..2HD) via per-block reduction + global atomics.
// Rows >= Mvalid (padding) are excluded from stats.
// ---------------------------------------------------------------------------
__global__ __launch_bounds__(256) void gemm_bf16(
    const ushort_t* __restrict__ A, int lda,
    const ushort_t* __restrict__ BT, int ldb,
    const float* __restrict__ bias,
    ushort_t* __restrict__ C, int ldc,
    int K, int doRelu,
    int doStats, float* __restrict__ stats, int Mvalid)
{
    extern __shared__ char smem[];
    ushort_t* As_sh = (ushort_t*)smem;          // 16 KB
    ushort_t* Bs_sh = As_sh + 8192;             // 16 KB
    ushort_t* Cs    = As_sh;                    // epilogue reuse: 128x128 bf16 = 32 KB
    float* ssum     = (float*)(smem + 32768);   // [4][128]
    float* ssq      = ssum + 512;               // [4][128]

    const int tid  = threadIdx.x;
    const int w    = tid >> 6;
    const int L    = tid & 63;
    const int lm   = L & 15;
    const int q    = L >> 4;
    const int row0 = blockIdx.x * 128;
    const int col0 = blockIdx.y * 128;

    f4v acc[2][8] = {};

    for (int k0 = 0; k0 < K; k0 += 64) {
#pragma unroll
        for (int i = 0; i < 4; ++i) {
            const int id = w * 4 + i;
            const int ks = id >> 3, tl = id & 7;
            const int kk = k0 + ks * 32 + q * 8;
            const ushort_t* ga = A  + (size_t)(row0 + tl * 16 + lm) * lda + kk;
            GLOAD_LDS16(ga, As_sh + id * 512);
            const ushort_t* gb = BT + (size_t)(col0 + tl * 16 + lm) * ldb + kk;
            GLOAD_LDS16(gb, Bs_sh + id * 512);
        }
        __syncthreads();
#pragma unroll
        for (int ks = 0; ks < 2; ++ks) {
            s8v a0 = *(const s8v*)&As_sh[(ks * 8 + 2 * w)     * 512 + L * 8];
            s8v a1 = *(const s8v*)&As_sh[(ks * 8 + 2 * w + 1) * 512 + L * 8];
#pragma unroll
            for (int nt = 0; nt < 8; ++nt) {
                s8v b = *(const s8v*)&Bs_sh[(ks * 8 + nt) * 512 + L * 8];
                acc[0][nt] = __builtin_amdgcn_mfma_f32_16x16x32_bf16(a0, b, acc[0][nt], 0, 0, 0);
                acc[1][nt] = __builtin_amdgcn_mfma_f32_16x16x32_bf16(a1, b, acc[1][nt], 0, 0, 0);
            }
        }
        __syncthreads();
    }

    // epilogue: bias + relu + cvt; C/D frag: col = lm, row = q*4 + r
    float cs[8] = {};
    float cq[8] = {};
#pragma unroll
    for (int mt = 0; mt < 2; ++mt) {
#pragma unroll
        for (int nt = 0; nt < 8; ++nt) {
            const float bj = bias[col0 + nt * 16 + lm];
            f4v v = acc[mt][nt];
#pragma unroll
            for (int r = 0; r < 4; ++r) {
                float f = v[r] + bj;
                if (doRelu) f = fmaxf(f, 0.f);
                const int row = (2 * w + mt) * 16 + q * 4 + r;
                const int col = nt * 16 + lm;
                Cs[row * 128 + col] = f2bf(f);
                if (doStats && (row0 + row) < Mvalid) {
                    cs[nt] += f;
                    cq[nt] += f * f;
                }
            }
        }
    }
    if (doStats) {
        // fold the 4 q-groups (lanes sharing lm): after this, lane with q==0
        // holds this wave's 32-row partial for col nt*16+lm.
#pragma unroll
        for (int nt = 0; nt < 8; ++nt) {
            float s = cs[nt], sq = cq[nt];
            s  += __shfl_xor(s, 16, 64);  s  += __shfl_xor(s, 32, 64);
            sq += __shfl_xor(sq, 16, 64); sq += __shfl_xor(sq, 32, 64);
            cs[nt] = s; cq[nt] = sq;
        }
    }
    __syncthreads();            // Cs ready (also orders ssum writes below)
    if (doStats && q == 0) {
#pragma unroll
        for (int nt = 0; nt < 8; ++nt) {
            ssum[w * 128 + nt * 16 + lm] = cs[nt];
            ssq [w * 128 + nt * 16 + lm] = cq[nt];
        }
    }
#pragma unroll
    for (int i = 0; i < 8; ++i) {
        const int idx = i * 256 + tid;
        const int row = idx >> 4, ch = idx & 15;
        s8v val = *(const s8v*)&Cs[row * 128 + ch * 8];
        *(s8v*)(C + (size_t)(row0 + row) * ldc + col0 + ch * 8) = val;
    }
    if (doStats) {
        __syncthreads();        // per-wave partials visible
        if (tid < 128) {
            const float s  = ssum[tid] + ssum[128 + tid] + ssum[256 + tid] + ssum[384 + tid];
            const float sq = ssq[tid]  + ssq[128 + tid]  + ssq[256 + tid]  + ssq[384 + tid];
            unsafeAtomicAdd(&stats[col0 + tid], s);
            unsafeAtomicAdd(&stats[HD + col0 + tid], sq);
        }
    }
}

// ---------------------------------------------------------------------------
__global__ __launch_bounds__(256) void transpose_cvt_kernel(
    const float* __restrict__ in, ushort_t* __restrict__ out, int R, int C)
{
    __shared__ float tile[32][33];
    const int bx = blockIdx.x * 32;
    const int by = blockIdx.y * 32;
    const int tx = threadIdx.x & 31;
    const int ty = threadIdx.x >> 5;
#pragma unroll
    for (int i = 0; i < 32; i += 8)
        tile[ty + i][tx] = in[(size_t)(by + ty + i) * C + bx + tx];
    __syncthreads();
#pragma unroll
    for (int i = 0; i < 32; i += 8)
        out[(size_t)(bx + ty + i) * R + by + tx] = f2bf(tile[tx][ty + i]);
}

__global__ __launch_bounds__(256) void cvt_kernel(
    const float* __restrict__ in, ushort_t* __restrict__ out, long n4)
{
    const long i = (long)blockIdx.x * 256 + threadIdx.x;
    if (i >= n4) return;
    const float4 v = ((const float4*)in)[i];
    ushort4 o;
    o.x = f2bf(v.x); o.y = f2bf(v.y); o.z = f2bf(v.z); o.w = f2bf(v.w);
    ((ushort4*)out)[i] = o;
}

__global__ __launch_bounds__(256) void zero_kernel(float* __restrict__ p, long n4)
{
    const long i = (long)blockIdx.x * 256 + threadIdx.x;
    if (i < n4) ((float4*)p)[i] = make_float4(0.f, 0.f, 0.f, 0.f);
}

// ---------------- CSR build (per call; edges are layer-invariant) -----------
__global__ __launch_bounds__(256) void hist_kernel(
    const int* __restrict__ dst, int* __restrict__ deg, int E)
{
    const int e = blockIdx.x * 256 + threadIdx.x;
    if (e < E) atomicAdd(&deg[dst[e]], 1);
}

__global__ __launch_bounds__(256) void scan1_kernel(
    const int* __restrict__ deg, int* __restrict__ partial,
    int* __restrict__ bsums, int n)
{
    __shared__ int tmp[256];
    const int i = blockIdx.x * 256 + threadIdx.x;
    const int v = (i < n) ? deg[i] : 0;
    tmp[threadIdx.x] = v;
    __syncthreads();
    for (int off = 1; off < 256; off <<= 1) {
        const int t = (threadIdx.x >= off) ? tmp[threadIdx.x - off] : 0;
        __syncthreads();
        tmp[threadIdx.x] += t;
        __syncthreads();
    }
    if (i < n) partial[i] = tmp[threadIdx.x] - v;
    if (threadIdx.x == 255) bsums[blockIdx.x] = tmp[255];
}

__global__ __launch_bounds__(512) void scan2_kernel(int* __restrict__ bsums, int nb)
{
    __shared__ int tmp[512];
    const int i = threadIdx.x;
    const int v = (i < nb) ? bsums[i] : 0;
    tmp[i] = v;
    __syncthreads();
    for (int off = 1; off < 512; off <<= 1) {
        const int t = (i >= off) ? tmp[i - off] : 0;
        __syncthreads();
        tmp[i] += t;
        __syncthreads();
    }
    if (i < nb) bsums[i] = tmp[i] - v;
}

__global__ __launch_bounds__(256) void scan3_kernel(
    const int* __restrict__ partial, const int* __restrict__ bsums,
    int* __restrict__ offs, int* __restrict__ cursor, int n)
{
    const int i = blockIdx.x * 256 + threadIdx.x;
    if (i < n) {
        const int o = partial[i] + bsums[blockIdx.x];
        offs[i] = o;
        cursor[i] = o;
    }
}

__global__ __launch_bounds__(256) void scatter_kernel(
    const int* __restrict__ src, const int* __restrict__ dst,
    int* __restrict__ cursor, int* __restrict__ srcSorted, int E)
{
    const int e = blockIdx.x * 256 + threadIdx.x;
    if (e >= E) return;
    const int p = atomicAdd(&cursor[dst[e]], 1);
    srcSorted[p] = src[e];
}

// ---------------------------------------------------------------------------
// z[n] = bf16( (1+eps)*h[n] + sum_{s in nbrs(n)} h[s] ), fp32 accumulate.
__global__ __launch_bounds__(256) void aggregate_kernel(
    const ushort_t* __restrict__ h, const int* __restrict__ offs,
    const int* __restrict__ deg, const int* __restrict__ srcSorted,
    const float* __restrict__ epsArr, int epsIdx,
    ushort_t* __restrict__ z)
{
    const int n = blockIdx.x * 4 + (threadIdx.x >> 6);
    const int t = threadIdx.x & 63;
    const int start = offs[n];
    const int dc = deg[n];
    float a0 = 0.f, a1 = 0.f, a2 = 0.f, a3 = 0.f;
    for (int j = 0; j < dc; ++j) {
        const int s = srcSorted[start + j];
        const ushort4 u = *(const ushort4*)(h + (size_t)s * HD + t * 4);
        a0 += bf2f(u.x); a1 += bf2f(u.y); a2 += bf2f(u.z); a3 += bf2f(u.w);
    }
    const float sc = 1.0f + epsArr[epsIdx];
    const ushort4 hs = *(const ushort4*)(h + (size_t)n * HD + t * 4);
    ushort4 o;
    o.x = f2bf(sc * bf2f(hs.x) + a0);
    o.y = f2bf(sc * bf2f(hs.y) + a1);
    o.z = f2bf(sc * bf2f(hs.z) + a2);
    o.w = f2bf(sc * bf2f(hs.w) + a3);
    *(ushort4*)(z + (size_t)n * HD + t * 4) = o;
}

// h = bf16( relu(gamma * (z - mu) * rsqrt(var+eps) + beta) )
__global__ __launch_bounds__(256) void bn_apply_kernel(
    const ushort_t* __restrict__ z, const float* __restrict__ stats,
    const float* __restrict__ gamma, const float* __restrict__ beta,
    ushort_t* __restrict__ hout, int Nn)
{
    const long total = (long)Nn * HD / 8;
    const long i = (long)blockIdx.x * 256 + threadIdx.x;
    if (i >= total) return;
    const int c = (int)((i * 8) % HD);
    const float invN = 1.0f / (float)Nn;
    ushort_t vin[8], vout[8];
    *(ushort4*)&vin[0] = ((const ushort4*)z)[i * 2];
    *(ushort4*)&vin[4] = ((const ushort4*)z)[i * 2 + 1];
#pragma unroll
    for (int j = 0; j < 8; ++j) {
        const float mu  = stats[c + j] * invN;
        const float var = stats[HD + c + j] * invN - mu * mu;
        const float inv = rsqrtf(var + BN_EPS);
        const float r   = gamma[c + j] * (bf2f(vin[j]) - mu) * inv + beta[c + j];
        vout[j] = f2bf(fmaxf(r, 0.f));
    }
    ((ushort4*)hout)[i * 2]     = *(ushort4*)&vout[0];
    ((ushort4*)hout)[i * 2 + 1] = *(ushort4*)&vout[4];
}

// ---------------------------------------------------------------------------
// Fused mean-pool + head. batch is SORTED: block g binary-searches its node
// range [start,end), accumulates column means (no atomics), then computes
// relu(mean @ Wp1 + bp1) @ Wp2 + bp2 in-block.
__global__ __launch_bounds__(256) void pool_head_kernel(
    const ushort_t* __restrict__ h, const int* __restrict__ batch,
    const float* __restrict__ Wp1, const float* __restrict__ bp1,
    const float* __restrict__ Wp2, const float* __restrict__ bp2,
    float* __restrict__ out)
{
    __shared__ float pool[HD];
    __shared__ float red[128];
    __shared__ int seg[2];
    const int g = blockIdx.x;
    const int t = threadIdx.x;
    if (t == 0) {
        int lo = 0, hi = NN;
        while (lo < hi) { const int m = (lo + hi) >> 1; if (batch[m] < g) lo = m + 1; else hi = m; }
        seg[0] = lo;
        hi = NN;
        while (lo < hi) { const int m = (lo + hi) >> 1; if (batch[m] < g + 1) lo = m + 1; else hi = m; }
        seg[1] = lo;
    }
    __syncthreads();
    const int start = seg[0], end = seg[1];
    float s = 0.f;
    for (int r = start; r < end; ++r)
        s += bf2f(h[(size_t)r * HD + t]);
    pool[t] = s * (1.0f / (float)max(end - start, 1));
    __syncthreads();
    if (t < 128) {
        float acc = 0.f;
#pragma unroll 4
        for (int k = 0; k < HD; ++k)
            acc += pool[k] * Wp1[k * 128 + t];
        red[t] = fmaxf(acc + bp1[t], 0.f) * Wp2[t];
    }
    __syncthreads();
    for (int sft = 64; sft > 0; sft >>= 1) {
        if (t < sft) red[t] += red[t + sft];
        __syncthreads();
    }
    if (t == 0) out[g] = red[0] + bp2[0];
}

// ---------------------------------------------------------------------------
extern "C" void kernel_launch(void* const* d_in, const int* in_sizes, int n_in,
                              void* d_out, int out_size, void* d_ws, size_t ws_size,
                              hipStream_t stream)
{
    const float* x     = (const float*)d_in[0];
    const int*   ei    = (const int*)  d_in[1];
    const int*   batch = (const int*)  d_in[2];
    const float* W_in  = (const float*)d_in[3];
    const float* b_in  = (const float*)d_in[4];
    const float* eps   = (const float*)d_in[5];
    const float* W1    = (const float*)d_in[6];
    const float* b1    = (const float*)d_in[7];
    const float* W2    = (const float*)d_in[8];
    const float* b2    = (const float*)d_in[9];
    const float* gamma = (const float*)d_in[10];
    const float* beta  = (const float*)d_in[11];
    const float* Wp1   = (const float*)d_in[12];
    const float* bp1   = (const float*)d_in[13];
    const float* Wp2   = (const float*)d_in[14];
    const float* bp2   = (const float*)d_in[15];

    const int* srcIdx = ei;
    const int* dstIdx = ei + EE;

    // ---- workspace layout ----
    char* p = (char*)d_ws;
    ushort_t* h       = (ushort_t*)p;  p += (size_t)NP * HD  * 2;
    ushort_t* z       = (ushort_t*)p;  p += (size_t)NP * HD  * 2;
    ushort_t* hidden  = (ushort_t*)p;  p += (size_t)NP * HD2 * 2;
    ushort_t* W1T     = (ushort_t*)p;  p += (size_t)NL * HD2 * HD * 2;
    ushort_t* W2T     = (ushort_t*)p;  p += (size_t)NL * HD * HD2 * 2;
    ushort_t* WinT    = (ushort_t*)p;  p += (size_t)HD * DIN * 2;
    int* deg          = (int*)p;       p += (size_t)NN * 4;
    int* partial      = (int*)p;       p += (size_t)NN * 4;
    int* bsums        = (int*)p;       p += 512 * 4;
    int* offs         = (int*)p;       p += (size_t)NN * 4;
    int* cursor       = (int*)p;       p += (size_t)NN * 4;
    int* srcSorted    = (int*)p;       p += (size_t)EE * 4;
    float* stats      = (float*)p;     p += 2 * HD * 4;
    ushort_t* x_bf    = hidden;        // GEMM0 A; clobbered later by GEMM1 out

    const int nb = (NN + 255) / 256;   // 391
    const int GEMM_LDS = 36864;        // 32KB tiles/Cs + 4KB stats partials

    // ---- weight conversion (bf16, transposed) ----
    transpose_cvt_kernel<<<dim3(HD / 32, DIN / 32), 256, 0, stream>>>(W_in, WinT, DIN, HD);
    for (int l = 0; l < NL; ++l) {
        transpose_cvt_kernel<<<dim3(HD2 / 32, HD / 32), 256, 0, stream>>>(
            W1 + (size_t)l * HD * HD2, W1T + (size_t)l * HD2 * HD, HD, HD2);
        transpose_cvt_kernel<<<dim3(HD / 32, HD2 / 32), 256, 0, stream>>>(
            W2 + (size_t)l * HD2 * HD, W2T + (size_t)l * HD * HD2, HD2, HD);
    }
    cvt_kernel<<<(int)(((long)NN * DIN / 4 + 255) / 256), 256, 0, stream>>>(
        x, x_bf, (long)NN * DIN / 4);

    // ---- CSR build (once; edges layer-invariant) ----
    zero_kernel<<<(NN / 4 + 255) / 256, 256, 0, stream>>>((float*)deg, NN / 4);
    hist_kernel<<<(EE + 255) / 256, 256, 0, stream>>>(dstIdx, deg, EE);
    scan1_kernel<<<nb, 256, 0, stream>>>(deg, partial, bsums, NN);
    scan2_kernel<<<1, 512, 0, stream>>>(bsums, nb);
    scan3_kernel<<<nb, 256, 0, stream>>>(partial, bsums, offs, cursor, NN);
    scatter_kernel<<<(EE + 255) / 256, 256, 0, stream>>>(srcIdx, dstIdx, cursor, srcSorted, EE);

    // ---- input projection: h = relu(x @ W_in + b_in) ----
    gemm_bf16<<<dim3(NP / 128, HD / 128), 256, GEMM_LDS, stream>>>(
        x_bf, DIN, WinT, DIN, b_in, h, HD, DIN, 1, 0, nullptr, 0);

    // ---- GIN layers ----
    for (int l = 0; l < NL; ++l) {
        aggregate_kernel<<<NN / 4, 256, 0, stream>>>(
            h, offs, deg, srcSorted, eps, l, z);

        gemm_bf16<<<dim3(NP / 128, HD2 / 128), 256, GEMM_LDS, stream>>>(
            z, HD, W1T + (size_t)l * HD2 * HD, HD,
            b1 + (size_t)l * HD2, hidden, HD2, HD, 1, 0, nullptr, 0);

        // stats must be zeroed before fused-stats GEMM2
        zero_kernel<<<1, 256, 0, stream>>>(stats, (2 * HD) / 4);
        gemm_bf16<<<dim3(NP / 128, HD / 128), 256, GEMM_LDS, stream>>>(
            hidden, HD2, W2T + (size_t)l * HD * HD2, HD2,
            b2 + (size_t)l * HD, z, HD, HD2, 0, 1, stats, NN);

        bn_apply_kernel<<<(int)(((long)NN * HD / 8 + 255) / 256), 256, 0, stream>>>(
            z, stats, gamma + (size_t)l * HD, beta + (size_t)l * HD, h, NN);
    }

    // ---- fused mean pool + head (batch sorted -> binary-searched segments) ----
    pool_head_kernel<<<NG, 256, 0, stream>>>(h, batch, Wp1, bp1, Wp2, bp2,
                                             (float*)d_out);
}

// Round 6
// 1062.571 us; speedup vs baseline: 10.5531x; 1.1514x over previous
//
#include <hip/hip_runtime.h>

#define NN 100000
#define NP 100096          // 782 * 128, padded row count
#define EE 300000
#define DIN 128
#define HD  256
#define HD2 512
#define NL  4
#define NG  512
#define BN_EPS 1e-5f

typedef __attribute__((ext_vector_type(8))) short s8v;      // bf16x8 frag (4 VGPRs)
typedef __attribute__((ext_vector_type(4))) float f4v;      // fp32x4 acc

typedef unsigned short ushort_t;

// float -> bf16, round-to-nearest-even
static __device__ inline ushort_t f2bf(float f) {
    unsigned u = __float_as_uint(f);
    unsigned r = (u + 0x7fffu + ((u >> 16) & 1u)) >> 16;
    return (ushort_t)r;
}
static __device__ inline float bf2f(ushort_t h) {
    return __uint_as_float(((unsigned)h) << 16);
}

// async global->LDS, 16B per lane; LDS dest = uniform base + lane*16
#define GLOAD_LDS16(g, l) __builtin_amdgcn_global_load_lds( \
    (const __attribute__((address_space(1))) unsigned int*)(const void*)(g), \
    (__attribute__((address_space(3))) unsigned int*)(void*)(l), 16, 0, 0)

// s_waitcnt immediates: vmcnt in bits[3:0]|[15:14], expcnt=7, lgkmcnt=15 (no wait)
#define WAITCNT_VM8 0xF78   // vmcnt(8)
#define WAITCNT_VM0 0xF70   // vmcnt(0)

// ---------------------------------------------------------------------------
// bf16 MFMA GEMM:  C[.,ldc](bf16) = act( A[.,lda](bf16) @ BT[.,ldb]^T + bias )
// Tile 128x128, BK=64, 256 threads = 4 waves. Fragment-major LDS.
// Software-pipelined: double-buffered LDS staging, rolling vmcnt(8) waits so
// the next tile's global_load_lds stays in flight across the barrier.
// doStats: column sum/sumsq of fp32 output into stats via block reduce+atomics.
// ---------------------------------------------------------------------------
__global__ __launch_bounds__(256) void gemm_bf16(
    const ushort_t* __restrict__ A, int lda,
    const ushort_t* __restrict__ BT, int ldb,
    const float* __restrict__ bias,
    ushort_t* __restrict__ C, int ldc,
    int K, int doRelu,
    int doStats, float* __restrict__ stats, int Mvalid)
{
    extern __shared__ char smem[];
    ushort_t* lds = (ushort_t*)smem;            // [buf][A 8192 | B 8192] x2 = 64 KB
    ushort_t* Cs  = lds;                        // epilogue reuse (32 KB, buf0)
    float* ssum   = (float*)(smem + 32768);     // epilogue reuse (buf1 area)
    float* ssq    = ssum + 512;

    const int tid  = threadIdx.x;
    const int w    = tid >> 6;
    const int L    = tid & 63;
    const int lm   = L & 15;
    const int q    = L >> 4;
    const int row0 = blockIdx.x * 128;
    const int col0 = blockIdx.y * 128;

    // per-thread staging addresses (A and B, 4 instrs each)
    const ushort_t* gAbase = A  + (size_t)lm * lda;
    const ushort_t* gBbase = BT + (size_t)lm * ldb;

    f4v acc[2][8] = {};

    const int niter = K >> 6;

    // ---- stage(buf, k0) ----
    #define STAGE(buf, k0) do {                                              \
        ushort_t* As_ = lds + (buf) * 16384;                                 \
        ushort_t* Bs_ = As_ + 8192;                                          \
        _Pragma("unroll")                                                    \
        for (int i_ = 0; i_ < 4; ++i_) {                                     \
            const int id_ = w * 4 + i_;                                      \
            const int ks_ = id_ >> 3, tl_ = id_ & 7;                         \
            const int kk_ = (k0) + ks_ * 32 + q * 8;                         \
            GLOAD_LDS16(gAbase + (size_t)(row0 + tl_ * 16) * lda + kk_,      \
                        As_ + id_ * 512);                                    \
            GLOAD_LDS16(gBbase + (size_t)(col0 + tl_ * 16) * ldb + kk_,      \
                        Bs_ + id_ * 512);                                    \
        }                                                                    \
    } while (0)

    STAGE(0, 0);
    if (niter > 1) STAGE(1, 64);

    for (int it = 0; it < niter; ++it) {
        // wait for stage(it); leave stage(it+1) in flight
        if (it + 1 < niter) __builtin_amdgcn_s_waitcnt(WAITCNT_VM8);
        else                __builtin_amdgcn_s_waitcnt(WAITCNT_VM0);
        __builtin_amdgcn_s_barrier();

        const ushort_t* Ab = lds + (it & 1) * 16384;
        const ushort_t* Bb = Ab + 8192;
#pragma unroll
        for (int ks = 0; ks < 2; ++ks) {
            s8v a0 = *(const s8v*)&Ab[(ks * 8 + 2 * w)     * 512 + L * 8];
            s8v a1 = *(const s8v*)&Ab[(ks * 8 + 2 * w + 1) * 512 + L * 8];
#pragma unroll
            for (int nt = 0; nt < 8; ++nt) {
                s8v b = *(const s8v*)&Bb[(ks * 8 + nt) * 512 + L * 8];
                acc[0][nt] = __builtin_amdgcn_mfma_f32_16x16x32_bf16(a0, b, acc[0][nt], 0, 0, 0);
                acc[1][nt] = __builtin_amdgcn_mfma_f32_16x16x32_bf16(a1, b, acc[1][nt], 0, 0, 0);
            }
        }
        __builtin_amdgcn_s_barrier();      // all waves done reading buf(it&1)
        if (it + 2 < niter) STAGE(it & 1, (it + 2) * 64);
    }
    #undef STAGE

    __syncthreads();    // drain everything before LDS reuse in epilogue

    // epilogue: bias + relu + cvt; C/D frag: col = lm, row = q*4 + r
    float cs[8] = {};
    float cq[8] = {};
#pragma unroll
    for (int mt = 0; mt < 2; ++mt) {
#pragma unroll
        for (int nt = 0; nt < 8; ++nt) {
            const float bj = bias[col0 + nt * 16 + lm];
            f4v v = acc[mt][nt];
#pragma unroll
            for (int r = 0; r < 4; ++r) {
                float f = v[r] + bj;
                if (doRelu) f = fmaxf(f, 0.f);
                const int row = (2 * w + mt) * 16 + q * 4 + r;
                const int col = nt * 16 + lm;
                Cs[row * 128 + col] = f2bf(f);
                if (doStats && (row0 + row) < Mvalid) {
                    cs[nt] += f;
                    cq[nt] += f * f;
                }
            }
        }
    }
    if (doStats) {
#pragma unroll
        for (int nt = 0; nt < 8; ++nt) {
            float s = cs[nt], sq = cq[nt];
            s  += __shfl_xor(s, 16, 64);  s  += __shfl_xor(s, 32, 64);
            sq += __shfl_xor(sq, 16, 64); sq += __shfl_xor(sq, 32, 64);
            cs[nt] = s; cq[nt] = sq;
        }
    }
    __syncthreads();
    if (doStats && q == 0) {
#pragma unroll
        for (int nt = 0; nt < 8; ++nt) {
            ssum[w * 128 + nt * 16 + lm] = cs[nt];
            ssq [w * 128 + nt * 16 + lm] = cq[nt];
        }
    }
#pragma unroll
    for (int i = 0; i < 8; ++i) {
        const int idx = i * 256 + tid;
        const int row = idx >> 4, ch = idx & 15;
        s8v val = *(const s8v*)&Cs[row * 128 + ch * 8];
        *(s8v*)(C + (size_t)(row0 + row) * ldc + col0 + ch * 8) = val;
    }
    if (doStats) {
        __syncthreads();
        if (tid < 128) {
            const float s  = ssum[tid] + ssum[128 + tid] + ssum[256 + tid] + ssum[384 + tid];
            const float sq = ssq[tid]  + ssq[128 + tid]  + ssq[256 + tid]  + ssq[384 + tid];
            unsafeAtomicAdd(&stats[col0 + tid], s);
            unsafeAtomicAdd(&stats[HD + col0 + tid], sq);
        }
    }
}

// ---------------------------------------------------------------------------
__global__ __launch_bounds__(256) void transpose_cvt_kernel(
    const float* __restrict__ in, ushort_t* __restrict__ out, int R, int C)
{
    __shared__ float tile[32][33];
    const int bx = blockIdx.x * 32;
    const int by = blockIdx.y * 32;
    const int tx = threadIdx.x & 31;
    const int ty = threadIdx.x >> 5;
#pragma unroll
    for (int i = 0; i < 32; i += 8)
        tile[ty + i][tx] = in[(size_t)(by + ty + i) * C + bx + tx];
    __syncthreads();
#pragma unroll
    for (int i = 0; i < 32; i += 8)
        out[(size_t)(bx + ty + i) * R + by + tx] = f2bf(tile[tx][ty + i]);
}

__global__ __launch_bounds__(256) void cvt_kernel(
    const float* __restrict__ in, ushort_t* __restrict__ out, long n4)
{
    const long i = (long)blockIdx.x * 256 + threadIdx.x;
    if (i >= n4) return;
    const float4 v = ((const float4*)in)[i];
    ushort4 o;
    o.x = f2bf(v.x); o.y = f2bf(v.y); o.z = f2bf(v.z); o.w = f2bf(v.w);
    ((ushort4*)out)[i] = o;
}

__global__ __launch_bounds__(256) void zero_kernel(float* __restrict__ p, long n4)
{
    const long i = (long)blockIdx.x * 256 + threadIdx.x;
    if (i < n4) ((float4*)p)[i] = make_float4(0.f, 0.f, 0.f, 0.f);
}

// identity scale/shift + zeroed stats (once per call, before layer 0)
__global__ __launch_bounds__(256) void init_bn_kernel(
    float* __restrict__ sscale, float* __restrict__ sshift,
    float* __restrict__ stats)
{
    const int t = threadIdx.x;
    sscale[t] = 1.f;
    sshift[t] = 0.f;
    stats[t] = 0.f;
    stats[HD + t] = 0.f;
}

// scale/shift from stats; re-zero stats for the next layer
__global__ __launch_bounds__(256) void bnprep_kernel(
    float* __restrict__ stats, const float* __restrict__ gamma,
    const float* __restrict__ beta, float* __restrict__ sscale,
    float* __restrict__ sshift, int Nn)
{
    const int t = threadIdx.x;
    const float invN = 1.0f / (float)Nn;
    const float mu  = stats[t] * invN;
    const float var = stats[HD + t] * invN - mu * mu;
    const float inv = rsqrtf(var + BN_EPS);
    const float sc  = gamma[t] * inv;
    sscale[t] = sc;
    sshift[t] = beta[t] - mu * sc;
    stats[t] = 0.f;
    stats[HD + t] = 0.f;
}

// ---------------- CSR build (per call; edges are layer-invariant) -----------
__global__ __launch_bounds__(256) void hist_kernel(
    const int* __restrict__ dst, int* __restrict__ deg, int E)
{
    const int e = blockIdx.x * 256 + threadIdx.x;
    if (e < E) atomicAdd(&deg[dst[e]], 1);
}

__global__ __launch_bounds__(256) void scan1_kernel(
    const int* __restrict__ deg, int* __restrict__ partial,
    int* __restrict__ bsums, int n)
{
    __shared__ int tmp[256];
    const int i = blockIdx.x * 256 + threadIdx.x;
    const int v = (i < n) ? deg[i] : 0;
    tmp[threadIdx.x] = v;
    __syncthreads();
    for (int off = 1; off < 256; off <<= 1) {
        const int t = (threadIdx.x >= off) ? tmp[threadIdx.x - off] : 0;
        __syncthreads();
        tmp[threadIdx.x] += t;
        __syncthreads();
    }
    if (i < n) partial[i] = tmp[threadIdx.x] - v;
    if (threadIdx.x == 255) bsums[blockIdx.x] = tmp[255];
}

__global__ __launch_bounds__(512) void scan2_kernel(int* __restrict__ bsums, int nb)
{
    __shared__ int tmp[512];
    const int i = threadIdx.x;
    const int v = (i < nb) ? bsums[i] : 0;
    tmp[i] = v;
    __syncthreads();
    for (int off = 1; off < 512; off <<= 1) {
        const int t = (i >= off) ? tmp[i - off] : 0;
        __syncthreads();
        tmp[i] += t;
        __syncthreads();
    }
    if (i < nb) bsums[i] = tmp[i] - v;
}

__global__ __launch_bounds__(256) void scan3_kernel(
    const int* __restrict__ partial, const int* __restrict__ bsums,
    int* __restrict__ offs, int* __restrict__ cursor, int n)
{
    const int i = blockIdx.x * 256 + threadIdx.x;
    if (i < n) {
        const int o = partial[i] + bsums[blockIdx.x];
        offs[i] = o;
        cursor[i] = o;
    }
}

__global__ __launch_bounds__(256) void scatter_kernel(
    const int* __restrict__ src, const int* __restrict__ dst,
    int* __restrict__ cursor, int* __restrict__ srcSorted, int E)
{
    const int e = blockIdx.x * 256 + threadIdx.x;
    if (e >= E) return;
    const int p = atomicAdd(&cursor[dst[e]], 1);
    srcSorted[p] = src[e];
}

// ---------------------------------------------------------------------------
// out[n] = bf16( (1+eps)*y[n] + sum_{s in nbrs(n)} y[s] ),
// where y[i] = relu( z[i]*sscale + sshift )  (BN applied on the fly).
__global__ __launch_bounds__(256) void aggregate_kernel(
    const ushort_t* __restrict__ z, const int* __restrict__ offs,
    const int* __restrict__ deg, const int* __restrict__ srcSorted,
    const float* __restrict__ epsArr, int epsIdx,
    const float* __restrict__ sscale, const float* __restrict__ sshift,
    ushort_t* __restrict__ out)
{
    const int n = blockIdx.x * 4 + (threadIdx.x >> 6);
    const int t = threadIdx.x & 63;
    const float4 sc = *(const float4*)(sscale + t * 4);
    const float4 sh = *(const float4*)(sshift + t * 4);
    const int start = offs[n];
    const int dc = deg[n];
    float a0 = 0.f, a1 = 0.f, a2 = 0.f, a3 = 0.f;
    for (int j = 0; j < dc; ++j) {
        const int s = srcSorted[start + j];
        const ushort4 u = *(const ushort4*)(z + (size_t)s * HD + t * 4);
        a0 += fmaxf(bf2f(u.x) * sc.x + sh.x, 0.f);
        a1 += fmaxf(bf2f(u.y) * sc.y + sh.y, 0.f);
        a2 += fmaxf(bf2f(u.z) * sc.z + sh.z, 0.f);
        a3 += fmaxf(bf2f(u.w) * sc.w + sh.w, 0.f);
    }
    const float se = 1.0f + epsArr[epsIdx];
    const ushort4 hs = *(const ushort4*)(z + (size_t)n * HD + t * 4);
    ushort4 o;
    o.x = f2bf(se * fmaxf(bf2f(hs.x) * sc.x + sh.x, 0.f) + a0);
    o.y = f2bf(se * fmaxf(bf2f(hs.y) * sc.y + sh.y, 0.f) + a1);
    o.z = f2bf(se * fmaxf(bf2f(hs.z) * sc.z + sh.z, 0.f) + a2);
    o.w = f2bf(se * fmaxf(bf2f(hs.w) * sc.w + sh.w, 0.f) + a3);
    *(ushort4*)(out + (size_t)n * HD + t * 4) = o;
}

// ---------------------------------------------------------------------------
// Fused mean-pool + head, with BN applied on the fly to z.
__global__ __launch_bounds__(256) void pool_head_kernel(
    const ushort_t* __restrict__ z, const int* __restrict__ batch,
    const float* __restrict__ sscale, const float* __restrict__ sshift,
    const float* __restrict__ Wp1, const float* __restrict__ bp1,
    const float* __restrict__ Wp2, const float* __restrict__ bp2,
    float* __restrict__ out)
{
    __shared__ float pool[HD];
    __shared__ float red[128];
    __shared__ int seg[2];
    const int g = blockIdx.x;
    const int t = threadIdx.x;
    if (t == 0) {
        int lo = 0, hi = NN;
        while (lo < hi) { const int m = (lo + hi) >> 1; if (batch[m] < g) lo = m + 1; else hi = m; }
        seg[0] = lo;
        hi = NN;
        while (lo < hi) { const int m = (lo + hi) >> 1; if (batch[m] < g + 1) lo = m + 1; else hi = m; }
        seg[1] = lo;
    }
    __syncthreads();
    const int start = seg[0], end = seg[1];
    const float sc = sscale[t], sh = sshift[t];
    float s = 0.f;
    for (int r = start; r < end; ++r)
        s += fmaxf(bf2f(z[(size_t)r * HD + t]) * sc + sh, 0.f);
    pool[t] = s * (1.0f / (float)max(end - start, 1));
    __syncthreads();
    if (t < 128) {
        float acc = 0.f;
#pragma unroll 4
        for (int k = 0; k < HD; ++k)
            acc += pool[k] * Wp1[k * 128 + t];
        red[t] = fmaxf(acc + bp1[t], 0.f) * Wp2[t];
    }
    __syncthreads();
    for (int sft = 64; sft > 0; sft >>= 1) {
        if (t < sft) red[t] += red[t + sft];
        __syncthreads();
    }
    if (t == 0) out[g] = red[0] + bp2[0];
}

// ---------------------------------------------------------------------------
extern "C" void kernel_launch(void* const* d_in, const int* in_sizes, int n_in,
                              void* d_out, int out_size, void* d_ws, size_t ws_size,
                              hipStream_t stream)
{
    const float* x     = (const float*)d_in[0];
    const int*   ei    = (const int*)  d_in[1];
    const int*   batch = (const int*)  d_in[2];
    const float* W_in  = (const float*)d_in[3];
    const float* b_in  = (const float*)d_in[4];
    const float* eps   = (const float*)d_in[5];
    const float* W1    = (const float*)d_in[6];
    const float* b1    = (const float*)d_in[7];
    const float* W2    = (const float*)d_in[8];
    const float* b2    = (const float*)d_in[9];
    const float* gamma = (const float*)d_in[10];
    const float* beta  = (const float*)d_in[11];
    const float* Wp1   = (const float*)d_in[12];
    const float* bp1   = (const float*)d_in[13];
    const float* Wp2   = (const float*)d_in[14];
    const float* bp2   = (const float*)d_in[15];

    const int* srcIdx = ei;
    const int* dstIdx = ei + EE;

    // ---- workspace layout ----
    char* p = (char*)d_ws;
    ushort_t* zbuf    = (ushort_t*)p;  p += (size_t)NP * HD  * 2;   // pre-BN acts
    ushort_t* abuf    = (ushort_t*)p;  p += (size_t)NP * HD  * 2;   // aggregate out
    ushort_t* hidden  = (ushort_t*)p;  p += (size_t)NP * HD2 * 2;   // MLP hidden (x_bf alias)
    ushort_t* W1T     = (ushort_t*)p;  p += (size_t)NL * HD2 * HD * 2;
    ushort_t* W2T     = (ushort_t*)p;  p += (size_t)NL * HD * HD2 * 2;
    ushort_t* WinT    = (ushort_t*)p;  p += (size_t)HD * DIN * 2;
    int* deg          = (int*)p;       p += (size_t)NN * 4;
    int* partial      = (int*)p;       p += (size_t)NN * 4;
    int* bsums        = (int*)p;       p += 512 * 4;
    int* offs         = (int*)p;       p += (size_t)NN * 4;
    int* cursor       = (int*)p;       p += (size_t)NN * 4;
    int* srcSorted    = (int*)p;       p += (size_t)EE * 4;
    float* stats      = (float*)p;     p += 2 * HD * 4;
    float* sscale     = (float*)p;     p += HD * 4;
    float* sshift     = (float*)p;     p += HD * 4;
    ushort_t* x_bf    = hidden;        // GEMM0 A; clobbered later by GEMM1 out

    const int nb = (NN + 255) / 256;   // 391
    const int GEMM_LDS = 65536;        // 2 x (16KB A + 16KB B); epilogue reuses

    // ---- BN identity + stats zero ----
    init_bn_kernel<<<1, 256, 0, stream>>>(sscale, sshift, stats);

    // ---- weight conversion (bf16, transposed) ----
    transpose_cvt_kernel<<<dim3(HD / 32, DIN / 32), 256, 0, stream>>>(W_in, WinT, DIN, HD);
    for (int l = 0; l < NL; ++l) {
        transpose_cvt_kernel<<<dim3(HD2 / 32, HD / 32), 256, 0, stream>>>(
            W1 + (size_t)l * HD * HD2, W1T + (size_t)l * HD2 * HD, HD, HD2);
        transpose_cvt_kernel<<<dim3(HD / 32, HD2 / 32), 256, 0, stream>>>(
            W2 + (size_t)l * HD2 * HD, W2T + (size_t)l * HD * HD2, HD2, HD);
    }
    cvt_kernel<<<(int)(((long)NN * DIN / 4 + 255) / 256), 256, 0, stream>>>(
        x, x_bf, (long)NN * DIN / 4);

    // ---- CSR build (once; edges layer-invariant) ----
    zero_kernel<<<(NN / 4 + 255) / 256, 256, 0, stream>>>((float*)deg, NN / 4);
    hist_kernel<<<(EE + 255) / 256, 256, 0, stream>>>(dstIdx, deg, EE);
    scan1_kernel<<<nb, 256, 0, stream>>>(deg, partial, bsums, NN);
    scan2_kernel<<<1, 512, 0, stream>>>(bsums, nb);
    scan3_kernel<<<nb, 256, 0, stream>>>(partial, bsums, offs, cursor, NN);
    scatter_kernel<<<(EE + 255) / 256, 256, 0, stream>>>(srcIdx, dstIdx, cursor, srcSorted, EE);

    // ---- input projection: zbuf = relu(x @ W_in + b_in)  (identity BN) ----
    gemm_bf16<<<dim3(NP / 128, HD / 128), 256, GEMM_LDS, stream>>>(
        x_bf, DIN, WinT, DIN, b_in, zbuf, HD, DIN, 1, 0, nullptr, 0);

    // ---- GIN layers ----
    for (int l = 0; l < NL; ++l) {
        aggregate_kernel<<<NN / 4, 256, 0, stream>>>(
            zbuf, offs, deg, srcSorted, eps, l, sscale, sshift, abuf);

        gemm_bf16<<<dim3(NP / 128, HD2 / 128), 256, GEMM_LDS, stream>>>(
            abuf, HD, W1T + (size_t)l * HD2 * HD, HD,
            b1 + (size_t)l * HD2, hidden, HD2, HD, 1, 0, nullptr, 0);

        gemm_bf16<<<dim3(NP / 128, HD / 128), 256, GEMM_LDS, stream>>>(
            hidden, HD2, W2T + (size_t)l * HD * HD2, HD2,
            b2 + (size_t)l * HD, zbuf, HD, HD2, 0, 1, stats, NN);

        bnprep_kernel<<<1, 256, 0, stream>>>(
            stats, gamma + (size_t)l * HD, beta + (size_t)l * HD, sscale, sshift, NN);
    }

    // ---- fused mean pool + head (BN on the fly) ----
    pool_head_kernel<<<NG, 256, 0, stream>>>(zbuf, batch, sscale, sshift,
                                             Wp1, bp1, Wp2, bp2, (float*)d_out);
}

// Round 7
// 1003.379 us; speedup vs baseline: 11.1756x; 1.0590x over previous
//
#include <hip/hip_runtime.h>

#define NN 100000
#define NP 100096          // 782 * 128, padded row count
#define EE 300000
#define DIN 128
#define HD  256
#define HD2 512
#define NL  4
#define NG  512
#define BN_EPS 1e-5f

typedef __attribute__((ext_vector_type(8))) short s8v;      // bf16x8 frag (4 VGPRs)
typedef __attribute__((ext_vector_type(4))) float f4v;      // fp32x4 acc

typedef unsigned short ushort_t;

// float -> bf16, round-to-nearest-even
static __device__ inline ushort_t f2bf(float f) {
    unsigned u = __float_as_uint(f);
    unsigned r = (u + 0x7fffu + ((u >> 16) & 1u)) >> 16;
    return (ushort_t)r;
}
static __device__ inline float bf2f(ushort_t h) {
    return __uint_as_float(((unsigned)h) << 16);
}

// async global->LDS, 16B per lane; LDS dest = uniform base + lane*16
#define GLOAD_LDS16(g, l) __builtin_amdgcn_global_load_lds( \
    (const __attribute__((address_space(1))) unsigned int*)(const void*)(g), \
    (__attribute__((address_space(3))) unsigned int*)(void*)(l), 16, 0, 0)

// s_waitcnt immediates: vmcnt in bits[3:0]|[15:14], expcnt=7, lgkmcnt=15
#define WAITCNT_VM4 0xF74   // vmcnt(4)
#define WAITCNT_VM0 0xF70   // vmcnt(0)

// ---------------------------------------------------------------------------
// bf16 MFMA GEMM:  C[.,ldc](bf16) = act( A[.,lda](bf16) @ BT[.,ldb]^T + bias )
// Tile 128x128, BK=32, 256 threads = 4 waves. Fragment-major LDS.
// Double-buffered (16 KB/stage, 32 KB total -> 4 blocks/CU), rolling vmcnt(4)
// waits so the next stage's global_load_lds stays in flight across barriers.
// doStats: column sum/sumsq of fp32 output into stats via block reduce+atomics.
// ---------------------------------------------------------------------------
__global__ __launch_bounds__(256) void gemm_bf16(
    const ushort_t* __restrict__ A, int lda,
    const ushort_t* __restrict__ BT, int ldb,
    const float* __restrict__ bias,
    ushort_t* __restrict__ C, int ldc,
    int K, int doRelu,
    int doStats, float* __restrict__ stats, int Mvalid)
{
    extern __shared__ char smem[];
    ushort_t* lds = (ushort_t*)smem;            // [buf][A 4096 | B 4096] x2 ushorts
    ushort_t* Cs  = lds;                        // epilogue reuse (32 KB)
    float* ssum   = (float*)(smem + 32768);     // 2 KB
    float* ssq    = ssum + 512;                 // 2 KB

    const int tid  = threadIdx.x;
    const int w    = tid >> 6;
    const int L    = tid & 63;
    const int lm   = L & 15;
    const int q    = L >> 4;
    const int row0 = blockIdx.x * 128;
    const int col0 = blockIdx.y * 128;

    const ushort_t* gAbase = A  + (size_t)lm * lda;
    const ushort_t* gBbase = BT + (size_t)lm * ldb;

    f4v acc[2][8] = {};

    const int niter = K >> 5;

    // stage(buf, k0): 8 A-tiles + 8 B-tiles of [16 rows x 32 cols] each;
    // 2 A + 2 B instrs per wave -> 4 outstanding per thread per stage.
    #define STAGE(buf, k0) do {                                              \
        ushort_t* As_ = lds + (buf) * 8192;                                  \
        ushort_t* Bs_ = As_ + 4096;                                          \
        _Pragma("unroll")                                                    \
        for (int i_ = 0; i_ < 2; ++i_) {                                     \
            const int tl_ = w * 2 + i_;                                      \
            const int kk_ = (k0) + q * 8;                                    \
            GLOAD_LDS16(gAbase + (size_t)(row0 + tl_ * 16) * lda + kk_,      \
                        As_ + tl_ * 512);                                    \
            GLOAD_LDS16(gBbase + (size_t)(col0 + tl_ * 16) * ldb + kk_,      \
                        Bs_ + tl_ * 512);                                    \
        }                                                                    \
    } while (0)

    STAGE(0, 0);
    if (niter > 1) STAGE(1, 32);

    for (int it = 0; it < niter; ++it) {
        if (it + 1 < niter) __builtin_amdgcn_s_waitcnt(WAITCNT_VM4);
        else                __builtin_amdgcn_s_waitcnt(WAITCNT_VM0);
        __builtin_amdgcn_s_barrier();

        const ushort_t* Ab = lds + (it & 1) * 8192;
        const ushort_t* Bb = Ab + 4096;
        s8v a0 = *(const s8v*)&Ab[(2 * w)     * 512 + L * 8];
        s8v a1 = *(const s8v*)&Ab[(2 * w + 1) * 512 + L * 8];
#pragma unroll
        for (int nt = 0; nt < 8; ++nt) {
            s8v b = *(const s8v*)&Bb[nt * 512 + L * 8];
            acc[0][nt] = __builtin_amdgcn_mfma_f32_16x16x32_bf16(a0, b, acc[0][nt], 0, 0, 0);
            acc[1][nt] = __builtin_amdgcn_mfma_f32_16x16x32_bf16(a1, b, acc[1][nt], 0, 0, 0);
        }
        __builtin_amdgcn_s_barrier();      // all waves done reading buf(it&1)
        if (it + 2 < niter) STAGE(it & 1, (it + 2) * 32);
    }
    #undef STAGE

    __syncthreads();    // drain before LDS reuse in epilogue

    // epilogue: bias + relu + cvt; C/D frag: col = lm, row = q*4 + r
    float cs[8] = {};
    float cq[8] = {};
#pragma unroll
    for (int mt = 0; mt < 2; ++mt) {
#pragma unroll
        for (int nt = 0; nt < 8; ++nt) {
            const float bj = bias[col0 + nt * 16 + lm];
            f4v v = acc[mt][nt];
#pragma unroll
            for (int r = 0; r < 4; ++r) {
                float f = v[r] + bj;
                if (doRelu) f = fmaxf(f, 0.f);
                const int row = (2 * w + mt) * 16 + q * 4 + r;
                const int col = nt * 16 + lm;
                Cs[row * 128 + col] = f2bf(f);
                if (doStats && (row0 + row) < Mvalid) {
                    cs[nt] += f;
                    cq[nt] += f * f;
                }
            }
        }
    }
    if (doStats) {
#pragma unroll
        for (int nt = 0; nt < 8; ++nt) {
            float s = cs[nt], sq = cq[nt];
            s  += __shfl_xor(s, 16, 64);  s  += __shfl_xor(s, 32, 64);
            sq += __shfl_xor(sq, 16, 64); sq += __shfl_xor(sq, 32, 64);
            cs[nt] = s; cq[nt] = sq;
        }
    }
    __syncthreads();
    if (doStats && q == 0) {
#pragma unroll
        for (int nt = 0; nt < 8; ++nt) {
            ssum[w * 128 + nt * 16 + lm] = cs[nt];
            ssq [w * 128 + nt * 16 + lm] = cq[nt];
        }
    }
#pragma unroll
    for (int i = 0; i < 8; ++i) {
        const int idx = i * 256 + tid;
        const int row = idx >> 4, ch = idx & 15;
        s8v val = *(const s8v*)&Cs[row * 128 + ch * 8];
        *(s8v*)(C + (size_t)(row0 + row) * ldc + col0 + ch * 8) = val;
    }
    if (doStats) {
        __syncthreads();
        if (tid < 128) {
            const float s  = ssum[tid] + ssum[128 + tid] + ssum[256 + tid] + ssum[384 + tid];
            const float sq = ssq[tid]  + ssq[128 + tid]  + ssq[256 + tid]  + ssq[384 + tid];
            unsafeAtomicAdd(&stats[col0 + tid], s);
            unsafeAtomicAdd(&stats[HD + col0 + tid], sq);
        }
    }
}

// ---------------------------------------------------------------------------
__global__ __launch_bounds__(256) void transpose_cvt_kernel(
    const float* __restrict__ in, ushort_t* __restrict__ out, int R, int C)
{
    __shared__ float tile[32][33];
    const int bx = blockIdx.x * 32;
    const int by = blockIdx.y * 32;
    const int tx = threadIdx.x & 31;
    const int ty = threadIdx.x >> 5;
#pragma unroll
    for (int i = 0; i < 32; i += 8)
        tile[ty + i][tx] = in[(size_t)(by + ty + i) * C + bx + tx];
    __syncthreads();
#pragma unroll
    for (int i = 0; i < 32; i += 8)
        out[(size_t)(bx + ty + i) * R + by + tx] = f2bf(tile[tx][ty + i]);
}

__global__ __launch_bounds__(256) void cvt_kernel(
    const float* __restrict__ in, ushort_t* __restrict__ out, long n4)
{
    const long i = (long)blockIdx.x * 256 + threadIdx.x;
    if (i >= n4) return;
    const float4 v = ((const float4*)in)[i];
    ushort4 o;
    o.x = f2bf(v.x); o.y = f2bf(v.y); o.z = f2bf(v.z); o.w = f2bf(v.w);
    ((ushort4*)out)[i] = o;
}

__global__ __launch_bounds__(256) void zero_kernel(float* __restrict__ p, long n4)
{
    const long i = (long)blockIdx.x * 256 + threadIdx.x;
    if (i < n4) ((float4*)p)[i] = make_float4(0.f, 0.f, 0.f, 0.f);
}

// identity scale/shift + zeroed stats (once per call, before layer 0)
__global__ __launch_bounds__(256) void init_bn_kernel(
    float* __restrict__ sscale, float* __restrict__ sshift,
    float* __restrict__ stats)
{
    const int t = threadIdx.x;
    sscale[t] = 1.f;
    sshift[t] = 0.f;
    stats[t] = 0.f;
    stats[HD + t] = 0.f;
}

// scale/shift from stats; re-zero stats for the next layer
__global__ __launch_bounds__(256) void bnprep_kernel(
    float* __restrict__ stats, const float* __restrict__ gamma,
    const float* __restrict__ beta, float* __restrict__ sscale,
    float* __restrict__ sshift, int Nn)
{
    const int t = threadIdx.x;
    const float invN = 1.0f / (float)Nn;
    const float mu  = stats[t] * invN;
    const float var = stats[HD + t] * invN - mu * mu;
    const float inv = rsqrtf(var + BN_EPS);
    const float sc  = gamma[t] * inv;
    sscale[t] = sc;
    sshift[t] = beta[t] - mu * sc;
    stats[t] = 0.f;
    stats[HD + t] = 0.f;
}

// ---------------- CSR build (per call; edges are layer-invariant) -----------
__global__ __launch_bounds__(256) void hist_kernel(
    const int* __restrict__ dst, int* __restrict__ deg, int E)
{
    const int e = blockIdx.x * 256 + threadIdx.x;
    if (e < E) atomicAdd(&deg[dst[e]], 1);
}

__global__ __launch_bounds__(256) void scan1_kernel(
    const int* __restrict__ deg, int* __restrict__ partial,
    int* __restrict__ bsums, int n)
{
    __shared__ int tmp[256];
    const int i = blockIdx.x * 256 + threadIdx.x;
    const int v = (i < n) ? deg[i] : 0;
    tmp[threadIdx.x] = v;
    __syncthreads();
    for (int off = 1; off < 256; off <<= 1) {
        const int t = (threadIdx.x >= off) ? tmp[threadIdx.x - off] : 0;
        __syncthreads();
        tmp[threadIdx.x] += t;
        __syncthreads();
    }
    if (i < n) partial[i] = tmp[threadIdx.x] - v;
    if (threadIdx.x == 255) bsums[blockIdx.x] = tmp[255];
}

__global__ __launch_bounds__(512) void scan2_kernel(int* __restrict__ bsums, int nb)
{
    __shared__ int tmp[512];
    const int i = threadIdx.x;
    const int v = (i < nb) ? bsums[i] : 0;
    tmp[i] = v;
    __syncthreads();
    for (int off = 1; off < 512; off <<= 1) {
        const int t = (i >= off) ? tmp[i - off] : 0;
        __syncthreads();
        tmp[i] += t;
        __syncthreads();
    }
    if (i < nb) bsums[i] = tmp[i] - v;
}

__global__ __launch_bounds__(256) void scan3_kernel(
    const int* __restrict__ partial, const int* __restrict__ bsums,
    int* __restrict__ offs, int* __restrict__ cursor, int n)
{
    const int i = blockIdx.x * 256 + threadIdx.x;
    if (i < n) {
        const int o = partial[i] + bsums[blockIdx.x];
        offs[i] = o;
        cursor[i] = o;
    }
}

__global__ __launch_bounds__(256) void scatter_kernel(
    const int* __restrict__ src, const int* __restrict__ dst,
    int* __restrict__ cursor, int* __restrict__ srcSorted, int E)
{
    const int e = blockIdx.x * 256 + threadIdx.x;
    if (e >= E) return;
    const int p = atomicAdd(&cursor[dst[e]], 1);
    srcSorted[p] = src[e];
}

// ---------------------------------------------------------------------------
// out[n] = bf16( (1+eps)*y[n] + sum_{s in nbrs(n)} y[s] ),
// where y[i] = relu( z[i]*sscale + sshift )  (BN applied on the fly).
__global__ __launch_bounds__(256) void aggregate_kernel(
    const ushort_t* __restrict__ z, const int* __restrict__ offs,
    const int* __restrict__ deg, const int* __restrict__ srcSorted,
    const float* __restrict__ epsArr, int epsIdx,
    const float* __restrict__ sscale, const float* __restrict__ sshift,
    ushort_t* __restrict__ out)
{
    const int n = blockIdx.x * 4 + (threadIdx.x >> 6);
    const int t = threadIdx.x & 63;
    const float4 sc = *(const float4*)(sscale + t * 4);
    const float4 sh = *(const float4*)(sshift + t * 4);
    const int start = offs[n];
    const int dc = deg[n];
    float a0 = 0.f, a1 = 0.f, a2 = 0.f, a3 = 0.f;
    for (int j = 0; j < dc; ++j) {
        const int s = srcSorted[start + j];
        const ushort4 u = *(const ushort4*)(z + (size_t)s * HD + t * 4);
        a0 += fmaxf(bf2f(u.x) * sc.x + sh.x, 0.f);
        a1 += fmaxf(bf2f(u.y) * sc.y + sh.y, 0.f);
        a2 += fmaxf(bf2f(u.z) * sc.z + sh.z, 0.f);
        a3 += fmaxf(bf2f(u.w) * sc.w + sh.w, 0.f);
    }
    const float se = 1.0f + epsArr[epsIdx];
    const ushort4 hs = *(const ushort4*)(z + (size_t)n * HD + t * 4);
    ushort4 o;
    o.x = f2bf(se * fmaxf(bf2f(hs.x) * sc.x + sh.x, 0.f) + a0);
    o.y = f2bf(se * fmaxf(bf2f(hs.y) * sc.y + sh.y, 0.f) + a1);
    o.z = f2bf(se * fmaxf(bf2f(hs.z) * sc.z + sh.z, 0.f) + a2);
    o.w = f2bf(se * fmaxf(bf2f(hs.w) * sc.w + sh.w, 0.f) + a3);
    *(ushort4*)(out + (size_t)n * HD + t * 4) = o;
}

// ---------------------------------------------------------------------------
// Fused mean-pool + head, BN on the fly. Wave w handles rows start+w, +4...;
// lane L handles cols 4L..4L+3 (ushort4). Two row-streams for ILP.
__global__ __launch_bounds__(256) void pool_head_kernel(
    const ushort_t* __restrict__ z, const int* __restrict__ batch,
    const float* __restrict__ sscale, const float* __restrict__ sshift,
    const float* __restrict__ Wp1, const float* __restrict__ bp1,
    const float* __restrict__ Wp2, const float* __restrict__ bp2,
    float* __restrict__ out)
{
    __shared__ float poolw[4][HD];   // per-wave partials
    __shared__ float pool[HD];
    __shared__ float red[128];
    __shared__ int seg[2];
    const int g = blockIdx.x;
    const int t = threadIdx.x;
    const int w = t >> 6;
    const int L = t & 63;
    if (t == 0) {
        int lo = 0, hi = NN;
        while (lo < hi) { const int m = (lo + hi) >> 1; if (batch[m] < g) lo = m + 1; else hi = m; }
        seg[0] = lo;
        hi = NN;
        while (lo < hi) { const int m = (lo + hi) >> 1; if (batch[m] < g + 1) lo = m + 1; else hi = m; }
        seg[1] = lo;
    }
    __syncthreads();
    const int start = seg[0], end = seg[1];
    const int c0 = L * 4;
    const float4 sc = *(const float4*)(sscale + c0);
    const float4 sh = *(const float4*)(sshift + c0);
    float a0 = 0.f, a1 = 0.f, a2 = 0.f, a3 = 0.f;
    float b0 = 0.f, b1 = 0.f, b2 = 0.f, b3 = 0.f;
    int r = start + w;
    for (; r + 4 < end; r += 8) {
        const ushort4 u = *(const ushort4*)(z + (size_t)r * HD + c0);
        const ushort4 v = *(const ushort4*)(z + (size_t)(r + 4) * HD + c0);
        a0 += fmaxf(bf2f(u.x) * sc.x + sh.x, 0.f);
        a1 += fmaxf(bf2f(u.y) * sc.y + sh.y, 0.f);
        a2 += fmaxf(bf2f(u.z) * sc.z + sh.z, 0.f);
        a3 += fmaxf(bf2f(u.w) * sc.w + sh.w, 0.f);
        b0 += fmaxf(bf2f(v.x) * sc.x + sh.x, 0.f);
        b1 += fmaxf(bf2f(v.y) * sc.y + sh.y, 0.f);
        b2 += fmaxf(bf2f(v.z) * sc.z + sh.z, 0.f);
        b3 += fmaxf(bf2f(v.w) * sc.w + sh.w, 0.f);
    }
    if (r < end) {
        const ushort4 u = *(const ushort4*)(z + (size_t)r * HD + c0);
        a0 += fmaxf(bf2f(u.x) * sc.x + sh.x, 0.f);
        a1 += fmaxf(bf2f(u.y) * sc.y + sh.y, 0.f);
        a2 += fmaxf(bf2f(u.z) * sc.z + sh.z, 0.f);
        a3 += fmaxf(bf2f(u.w) * sc.w + sh.w, 0.f);
    }
    poolw[w][c0 + 0] = a0 + b0;
    poolw[w][c0 + 1] = a1 + b1;
    poolw[w][c0 + 2] = a2 + b2;
    poolw[w][c0 + 3] = a3 + b3;
    __syncthreads();
    const float invC = 1.0f / (float)max(end - start, 1);
    pool[t] = (poolw[0][t] + poolw[1][t] + poolw[2][t] + poolw[3][t]) * invC;
    __syncthreads();
    if (t < 128) {
        float acc = 0.f;
#pragma unroll 4
        for (int k = 0; k < HD; ++k)
            acc += pool[k] * Wp1[k * 128 + t];
        red[t] = fmaxf(acc + bp1[t], 0.f) * Wp2[t];
    }
    __syncthreads();
    for (int sft = 64; sft > 0; sft >>= 1) {
        if (t < sft) red[t] += red[t + sft];
        __syncthreads();
    }
    if (t == 0) out[g] = red[0] + bp2[0];
}

// ---------------------------------------------------------------------------
extern "C" void kernel_launch(void* const* d_in, const int* in_sizes, int n_in,
                              void* d_out, int out_size, void* d_ws, size_t ws_size,
                              hipStream_t stream)
{
    const float* x     = (const float*)d_in[0];
    const int*   ei    = (const int*)  d_in[1];
    const int*   batch = (const int*)  d_in[2];
    const float* W_in  = (const float*)d_in[3];
    const float* b_in  = (const float*)d_in[4];
    const float* eps   = (const float*)d_in[5];
    const float* W1    = (const float*)d_in[6];
    const float* b1    = (const float*)d_in[7];
    const float* W2    = (const float*)d_in[8];
    const float* b2    = (const float*)d_in[9];
    const float* gamma = (const float*)d_in[10];
    const float* beta  = (const float*)d_in[11];
    const float* Wp1   = (const float*)d_in[12];
    const float* bp1   = (const float*)d_in[13];
    const float* Wp2   = (const float*)d_in[14];
    const float* bp2   = (const float*)d_in[15];

    const int* srcIdx = ei;
    const int* dstIdx = ei + EE;

    // ---- workspace layout ----
    char* p = (char*)d_ws;
    ushort_t* zbuf    = (ushort_t*)p;  p += (size_t)NP * HD  * 2;   // pre-BN acts
    ushort_t* abuf    = (ushort_t*)p;  p += (size_t)NP * HD  * 2;   // aggregate out
    ushort_t* hidden  = (ushort_t*)p;  p += (size_t)NP * HD2 * 2;   // MLP hidden (x_bf alias)
    ushort_t* W1T     = (ushort_t*)p;  p += (size_t)NL * HD2 * HD * 2;
    ushort_t* W2T     = (ushort_t*)p;  p += (size_t)NL * HD * HD2 * 2;
    ushort_t* WinT    = (ushort_t*)p;  p += (size_t)HD * DIN * 2;
    int* deg          = (int*)p;       p += (size_t)NN * 4;
    int* partial      = (int*)p;       p += (size_t)NN * 4;
    int* bsums        = (int*)p;       p += 512 * 4;
    int* offs         = (int*)p;       p += (size_t)NN * 4;
    int* cursor       = (int*)p;       p += (size_t)NN * 4;
    int* srcSorted    = (int*)p;       p += (size_t)EE * 4;
    float* stats      = (float*)p;     p += 2 * HD * 4;
    float* sscale     = (float*)p;     p += HD * 4;
    float* sshift     = (float*)p;     p += HD * 4;
    ushort_t* x_bf    = hidden;        // GEMM0 A; clobbered later by GEMM1 out

    const int nb = (NN + 255) / 256;   // 391
    const int GEMM_LDS = 36864;        // 32KB dbuf/Cs + 4KB stats partials

    // ---- BN identity + stats zero ----
    init_bn_kernel<<<1, 256, 0, stream>>>(sscale, sshift, stats);

    // ---- weight conversion (bf16, transposed) ----
    transpose_cvt_kernel<<<dim3(HD / 32, DIN / 32), 256, 0, stream>>>(W_in, WinT, DIN, HD);
    for (int l = 0; l < NL; ++l) {
        transpose_cvt_kernel<<<dim3(HD2 / 32, HD / 32), 256, 0, stream>>>(
            W1 + (size_t)l * HD * HD2, W1T + (size_t)l * HD2 * HD, HD, HD2);
        transpose_cvt_kernel<<<dim3(HD / 32, HD2 / 32), 256, 0, stream>>>(
            W2 + (size_t)l * HD2 * HD, W2T + (size_t)l * HD * HD2, HD2, HD);
    }
    cvt_kernel<<<(int)(((long)NN * DIN / 4 + 255) / 256), 256, 0, stream>>>(
        x, x_bf, (long)NN * DIN / 4);

    // ---- CSR build (once; edges layer-invariant) ----
    zero_kernel<<<(NN / 4 + 255) / 256, 256, 0, stream>>>((float*)deg, NN / 4);
    hist_kernel<<<(EE + 255) / 256, 256, 0, stream>>>(dstIdx, deg, EE);
    scan1_kernel<<<nb, 256, 0, stream>>>(deg, partial, bsums, NN);
    scan2_kernel<<<1, 512, 0, stream>>>(bsums, nb);
    scan3_kernel<<<nb, 256, 0, stream>>>(partial, bsums, offs, cursor, NN);
    scatter_kernel<<<(EE + 255) / 256, 256, 0, stream>>>(srcIdx, dstIdx, cursor, srcSorted, EE);

    // ---- input projection: zbuf = relu(x @ W_in + b_in)  (identity BN) ----
    gemm_bf16<<<dim3(NP / 128, HD / 128), 256, GEMM_LDS, stream>>>(
        x_bf, DIN, WinT, DIN, b_in, zbuf, HD, DIN, 1, 0, nullptr, 0);

    // ---- GIN layers ----
    for (int l = 0; l < NL; ++l) {
        aggregate_kernel<<<NN / 4, 256, 0, stream>>>(
            zbuf, offs, deg, srcSorted, eps, l, sscale, sshift, abuf);

        gemm_bf16<<<dim3(NP / 128, HD2 / 128), 256, GEMM_LDS, stream>>>(
            abuf, HD, W1T + (size_t)l * HD2 * HD, HD,
            b1 + (size_t)l * HD2, hidden, HD2, HD, 1, 0, nullptr, 0);

        gemm_bf16<<<dim3(NP / 128, HD / 128), 256, GEMM_LDS, stream>>>(
            hidden, HD2, W2T + (size_t)l * HD * HD2, HD2,
            b2 + (size_t)l * HD, zbuf, HD, HD2, 0, 1, stats, NN);

        bnprep_kernel<<<1, 256, 0, stream>>>(
            stats, gamma + (size_t)l * HD, beta + (size_t)l * HD, sscale, sshift, NN);
    }

    // ---- fused mean pool + head (BN on the fly) ----
    pool_head_kernel<<<NG, 256, 0, stream>>>(zbuf, batch, sscale, sshift,
                                             Wp1, bp1, Wp2, bp2, (float*)d_out);
}